// Round 5
// baseline (308.429 us; speedup 1.0000x reference)
//
#include <hip/hip_runtime.h>

// ---------------------------------------------------------------------------
// TimeMoeAttention: X@Wq/Wk/Wv + bias -> continuous-time RoPE -> causal GQA
// attention -> @Wo.  B=2, S=2048, H=2048, NH=16, NKV=4, HD=128.
// I/O fp32; internal bf16 + fp32 MFMA accumulation.
// R15: attn wave-fattening. R14 post-mortem: Ps XOR-swizzle caused 1.08M
//      bank conflicts (8 bank-slots x different rows) and 2x81920B did not
//      co-fit (occupancy unchanged) -> both reverted to R13's proven forms.
//      R13/R14 plateau diagnosis: LDS-issue-rate bound (~38 b128-class ops
//      x ~12cyc per wave-chunk; K/V frag reads duplicated per wave).  Fix:
//      4 waves x 32 q-rows (256 thr) -- each K/V fragment read ONCE per
//      wave, used for both 16-row m-subtiles: LDS ops/block-chunk 304->176.
//      MFMA/VALU per CU unchanged.  All else byte-identical to R13.
// ---------------------------------------------------------------------------

#define S_LEN 2048
#define BATCH 2
#define NH    16
#define NKV   4
#define HD    128

typedef float  f32x4  __attribute__((ext_vector_type(4)));
typedef __bf16 bf16x8 __attribute__((ext_vector_type(8)));
typedef __bf16 bf16x4 __attribute__((ext_vector_type(4)));
typedef unsigned int u32x4 __attribute__((ext_vector_type(4)));
typedef unsigned int u32x2 __attribute__((ext_vector_type(2)));

__device__ inline unsigned short f2bf(float f) {
    unsigned u = __builtin_bit_cast(unsigned, f);
    unsigned r = (u + 0x7fffu + ((u >> 16) & 1u)) >> 16;   // RNE
    return (unsigned short)r;
}

// async global->LDS, 16 bytes per lane (dest = wave-uniform base + lane*16)
__device__ inline void gload_lds16(const void* g, void* l) {
    __builtin_amdgcn_global_load_lds(
        (const __attribute__((address_space(1))) unsigned int*)g,
        (__attribute__((address_space(3))) unsigned int*)l, 16, 0, 0);
}

// ---------------------------------------------------------------------------
// Fused transposes: wq|wk|wv (fp32) -> Wt (bf16, [3072][2048]).  z selects.
// ---------------------------------------------------------------------------
__global__ void transpose_qkv(const float* __restrict__ wq,
                              const float* __restrict__ wk,
                              const float* __restrict__ wv,
                              unsigned short* __restrict__ Wt) {
    int z = blockIdx.z;
    const float* src = (z == 0) ? wq : ((z == 1) ? wk : wv);
    int C = (z == 0) ? 2048 : 512;
    long doff = (z == 0) ? 0L : ((z == 1) ? 2048L * 2048 : 2560L * 2048);
    int bx = blockIdx.x * 32, by = blockIdx.y * 32;
    if (bx >= C) return;
    __shared__ unsigned short t[32][33];
    int x = threadIdx.x, y0 = threadIdx.y;
    #pragma unroll
    for (int i = 0; i < 4; i++) {
        int y = y0 + i * 8;
        t[y][x] = f2bf(src[(long)(by + y) * C + bx + x]);
    }
    __syncthreads();
    #pragma unroll
    for (int i = 0; i < 4; i++) {
        int y = y0 + i * 8;
        Wt[doff + (long)(bx + y) * 2048 + by + x] = t[x][y];
    }
}

// single fp32->bf16 transpose (for wo, launched after gemm1 frees Wt)
__global__ void transpose_to_bf16(const float* __restrict__ src,
                                  unsigned short* __restrict__ dst,
                                  int R, int C, long dst_off, int ldd) {
    __shared__ unsigned short t[32][33];
    int bx = blockIdx.x * 32, by = blockIdx.y * 32;
    int x = threadIdx.x, y0 = threadIdx.y;
    #pragma unroll
    for (int i = 0; i < 4; i++) {
        int y = y0 + i * 8;
        t[y][x] = f2bf(src[(long)(by + y) * C + bx + x]);
    }
    __syncthreads();
    #pragma unroll
    for (int i = 0; i < 4; i++) {
        int y = y0 + i * 8;
        dst[dst_off + (long)(bx + y) * ldd + by + x] = t[x][y];
    }
}

// ---------------------------------------------------------------------------
// Prep: X fp32->bf16 (all 4096 blocks), bias concat (blocks 0-11),
// rope table Tab[4096 tokens][64 freqs x (cs,sn) bf16 pairs] (blocks 0-1023).
// ---------------------------------------------------------------------------
__global__ __launch_bounds__(256) void prep_kernel(
        const float* __restrict__ X, unsigned short* __restrict__ Xb,
        const float* __restrict__ bq, const float* __restrict__ bk,
        const float* __restrict__ bv, float* __restrict__ bsf,
        const float* __restrict__ tv, const float* __restrict__ rw,
        unsigned int* __restrict__ Tab) {
    int bi = blockIdx.x, tid = threadIdx.x;
    long i = ((long)bi * 256 + tid) * 8;
    {
        f32x4 a = *(const f32x4*)&X[i];
        f32x4 b = *(const f32x4*)&X[i + 4];
        u32x4 r;
        r.x = (unsigned)f2bf(a[0]) | ((unsigned)f2bf(a[1]) << 16);
        r.y = (unsigned)f2bf(a[2]) | ((unsigned)f2bf(a[3]) << 16);
        r.z = (unsigned)f2bf(b[0]) | ((unsigned)f2bf(b[1]) << 16);
        r.w = (unsigned)f2bf(b[2]) | ((unsigned)f2bf(b[3]) << 16);
        *(u32x4*)&Xb[i] = r;
    }
    if (bi < 12) {
        int ib = bi * 256 + tid;
        bsf[ib] = (ib < 2048) ? bq[ib] : ((ib < 2560) ? bk[ib - 2048] : bv[ib - 2560]);
    }
    if (bi < 1024) {
        int m = bi * 4 + (tid >> 6);
        int fi = tid & 63;
        float t = tv[m];
        float f = t * powf(10000.f, -(float)fi / 64.f) * rw[fi];
        Tab[m * 64 + fi] = (unsigned)f2bf(cosf(f)) | ((unsigned)f2bf(sinf(f)) << 16);
    }
}

// ---------------------------------------------------------------------------
// 256x256 8-phase GEMM machinery (R11; see phase table in git history).
// LDS slots: A(buf,ks) at buf*16384+ks*8192, B at +32768.  Slot=256rx32k,
// XOR-swizzled kgrp^((row>>1)&3).  Staging: linear LDS dest + pre-swizzled
// global column.  vmcnt(6) at phases 4/8 only.
// ---------------------------------------------------------------------------
__device__ __forceinline__ void stage_half(const unsigned short* __restrict__ G,
        int baseRow, long kc, unsigned short* slot, int r0, int c0, int tid) {
    gload_lds16(&G[(long)(baseRow + r0) * 2048 + kc + c0], &slot[tid * 8]);
    gload_lds16(&G[(long)(baseRow + r0 + 128) * 2048 + kc + c0], &slot[4096 + tid * 8]);
}

#define STG_A(buf, ks, kt) \
    stage_half(A,  m0, (long)(kt) * 64 + (ks) * 32, &sm[(buf) * 16384 + (ks) * 8192], r0s, c0s, tid)
#define STG_B(buf, ks, kt) \
    stage_half(Bt, n0, (long)(kt) * 64 + (ks) * 32, &sm[32768 + (buf) * 16384 + (ks) * 8192], r0s, c0s, tid)

#define NOPV ((void)0)
#define VM6  asm volatile("s_waitcnt vmcnt(6)" ::: "memory")

#define PH(buf, ks, mh, RDB, STG, VM)                                          \
    {                                                                          \
        const int sb_ = (buf) * 16384 + (ks) * 8192;                           \
        bf16x8 a0 = *(const bf16x8*)&sm[sb_ + abase + (mh) * 2048];            \
        bf16x8 a1 = *(const bf16x8*)&sm[sb_ + abase + (mh) * 2048 + 512];      \
        bf16x8 a2 = *(const bf16x8*)&sm[sb_ + abase + (mh) * 2048 + 1024];     \
        bf16x8 a3 = *(const bf16x8*)&sm[sb_ + abase + (mh) * 2048 + 1536];     \
        if (RDB) {                                                             \
            b0 = *(const bf16x8*)&sm[sb_ + bbase];                             \
            b1 = *(const bf16x8*)&sm[sb_ + bbase + 512];                       \
            b2 = *(const bf16x8*)&sm[sb_ + bbase + 1024];                      \
            b3 = *(const bf16x8*)&sm[sb_ + bbase + 1536];                      \
        }                                                                      \
        STG;                                                                   \
        VM;                                                                    \
        __builtin_amdgcn_s_barrier();                                          \
        asm volatile("s_waitcnt lgkmcnt(0)" ::: "memory");                     \
        __builtin_amdgcn_sched_barrier(0);                                     \
        __builtin_amdgcn_s_setprio(1);                                         \
        _Pragma("unroll") for (int mi = 0; mi < 4; ++mi) {                     \
            bf16x8 am = (mi == 0) ? a0 : (mi == 1) ? a1 : (mi == 2) ? a2 : a3; \
            acc[(mh) * 4 + mi][0] = __builtin_amdgcn_mfma_f32_16x16x32_bf16(   \
                am, b0, acc[(mh) * 4 + mi][0], 0, 0, 0);                       \
            acc[(mh) * 4 + mi][1] = __builtin_amdgcn_mfma_f32_16x16x32_bf16(   \
                am, b1, acc[(mh) * 4 + mi][1], 0, 0, 0);                       \
            acc[(mh) * 4 + mi][2] = __builtin_amdgcn_mfma_f32_16x16x32_bf16(   \
                am, b2, acc[(mh) * 4 + mi][2], 0, 0, 0);                       \
            acc[(mh) * 4 + mi][3] = __builtin_amdgcn_mfma_f32_16x16x32_bf16(   \
                am, b3, acc[(mh) * 4 + mi][3], 0, 0, 0);                       \
        }                                                                      \
        __builtin_amdgcn_s_setprio(0);                                         \
        __builtin_amdgcn_s_barrier();                                          \
    }

#define GEMM_PRO_LOOP(NIT)                                                     \
    STG_B(0, 0, 0); STG_A(0, 0, 0); STG_B(0, 1, 0); STG_A(0, 1, 0);            \
    STG_B(1, 0, 1); STG_A(1, 0, 1); STG_B(1, 1, 1);                            \
    asm volatile("s_waitcnt vmcnt(6)" ::: "memory");                           \
    __builtin_amdgcn_s_barrier();                                              \
    for (int it = 0; it < (NIT); ++it) {                                       \
        const int t1  = 2 * it + 1;                                            \
        const int tn0 = (it < (NIT) - 1) ? 2 * it + 2 : 2 * (NIT) - 1;         \
        const int tn1 = (it < (NIT) - 1) ? 2 * it + 3 : 2 * (NIT) - 1;         \
        PH(0, 0, 0, 1, STG_A(1, 1, t1),  NOPV);                                \
        PH(0, 0, 1, 0, STG_B(0, 0, tn0), NOPV);                                \
        PH(0, 1, 0, 1, STG_A(0, 0, tn0), NOPV);                                \
        PH(0, 1, 1, 0, STG_B(0, 1, tn0), VM6);                                 \
        PH(1, 0, 0, 1, STG_A(0, 1, tn0), NOPV);                                \
        PH(1, 0, 1, 0, STG_B(1, 0, tn1), NOPV);                                \
        PH(1, 1, 0, 1, STG_A(1, 0, tn1), NOPV);                                \
        PH(1, 1, 1, 0, STG_B(1, 1, tn1), VM6);                                 \
    }

// ---------------------------------------------------------------------------
// GEMM1 + bias + RoPE fused, 256x256 8-phase schedule (R11).
// Grid (12,16): bx 0..7 -> Q heads 2bx,2bx+1; 8,9 -> K; 10,11 -> V.
// ---------------------------------------------------------------------------
__global__ __launch_bounds__(512, 2) void gemm_qkv_rope(
        const unsigned short* __restrict__ A,
        const unsigned short* __restrict__ Bt,
        const float* __restrict__ bsf,
        const unsigned int* __restrict__ Tab,
        unsigned short* __restrict__ Qr,
        unsigned short* __restrict__ Kr,
        unsigned short* __restrict__ Vt) {
    __shared__ __align__(16) unsigned short sm[65536];   // 128 KiB

    const int tid = threadIdx.x;
    const int wid = tid >> 6, lane = tid & 63, quad = lane >> 4, l16 = lane & 15;
    const int wr = wid >> 2, wc = wid & 3;               // 2M x 4N waves

    // XCD-aware bijective swizzle (192 blocks, 192 % 8 == 0)
    const int u   = blockIdx.y * 12 + blockIdx.x;
    const int swz = (u & 7) * 24 + (u >> 3);
    const int bx  = swz % 12;
    const int m0  = (swz / 12) * 256;
    const int n0  = bx * 256;

    // fragment-read addressing (XOR bank swizzle on the k-group)
    const int sg    = (quad ^ ((l16 >> 1) & 3)) * 8;
    const int abase = wr * 4096 + l16 * 32 + sg;
    const int bbase = 32768 + wc * 2048 + l16 * 32 + sg;

    // staging addressing: linear LDS dest, pre-swizzled global column
    const int r0s = tid >> 2;
    const int c0s = ((tid & 3) ^ ((r0s >> 1) & 3)) * 8;

    f32x4 acc[8][4];
    #pragma unroll
    for (int i = 0; i < 8; i++)
        #pragma unroll
        for (int j = 0; j < 4; j++)
            #pragma unroll
            for (int c = 0; c < 4; c++) acc[i][j][c] = 0.f;
    bf16x8 b0 = {}, b1 = {}, b2 = {}, b3 = {};

    GEMM_PRO_LOOP(16)

    // drain stray prefetches before reusing smem for the epilogue
    asm volatile("s_waitcnt vmcnt(0)" ::: "memory");
    __syncthreads();

    // ---- fused epilogue: bias + RoPE (Q,K) / transpose (V), 8x32 tokens ----
    float* Ep = (float*)sm;
    const int EPLD = 264;                                // 256 + 8 pad
    float bv4[4];
    #pragma unroll
    for (int ni = 0; ni < 4; ++ni) bv4[ni] = bsf[n0 + wc * 64 + ni * 16 + l16];
    const bool isV = (bx >= 10);
    const float qs = (bx < 8) ? (0.08838834764831845f * 1.4426950408889634f) : 1.0f;

    const int lt = tid >> 4, hh = (tid >> 3) & 1, jj = tid & 7, j0 = jj * 8;
    const int vd = tid >> 1, vsh = tid & 1;

    #pragma unroll
    for (int p = 0; p < 8; ++p) {
        if (wr == (p >> 2)) {
            #pragma unroll
            for (int f = 0; f < 2; ++f) {
                #pragma unroll
                for (int ni = 0; ni < 4; ++ni)
                    #pragma unroll
                    for (int r = 0; r < 4; ++r)
                        Ep[(f * 16 + quad * 4 + r) * EPLD + wc * 64 + ni * 16 + l16] =
                            acc[(p & 3) * 2 + f][ni][r] + bv4[ni];
            }
        }
        __syncthreads();
        if (!isV) {
            const int gm = m0 + p * 32 + lt;
            const int bb = gm >> 11, s = gm & 2047;
            unsigned short* dst = (bx < 8)
                ? Qr + ((long)(bb * NH + bx * 2 + hh) * S_LEN + s) * HD
                : Kr + ((long)(bb * NKV + (bx - 8) * 2 + hh) * S_LEN + s) * HD;
            u32x4 t0 = *(const u32x4*)&Tab[(long)gm * 64 + j0];
            u32x4 t1v = *(const u32x4*)&Tab[(long)gm * 64 + j0 + 4];
            f32x4 x1a = *(f32x4*)&Ep[lt * EPLD + hh * 128 + j0];
            f32x4 x1b = *(f32x4*)&Ep[lt * EPLD + hh * 128 + j0 + 4];
            f32x4 x2a = *(f32x4*)&Ep[lt * EPLD + hh * 128 + 64 + j0];
            f32x4 x2b = *(f32x4*)&Ep[lt * EPLD + hh * 128 + 64 + j0 + 4];
            f32x4 la, lb, ha, hb;
            #pragma unroll
            for (int e = 0; e < 4; e++) {
                float ca = __builtin_bit_cast(float, t0[e] << 16);
                float sa = __builtin_bit_cast(float, t0[e] & 0xffff0000u);
                float cb = __builtin_bit_cast(float, t1v[e] << 16);
                float sbv = __builtin_bit_cast(float, t1v[e] & 0xffff0000u);
                la[e] = (x1a[e] * ca - x2a[e] * sa) * qs;
                ha[e] = (x2a[e] * ca + x1a[e] * sa) * qs;
                lb[e] = (x1b[e] * cb - x2b[e] * sbv) * qs;
                hb[e] = (x2b[e] * cb + x1b[e] * sbv) * qs;
            }
            u32x4 lo, hi;
            lo.x = (unsigned)f2bf(la[0]) | ((unsigned)f2bf(la[1]) << 16);
            lo.y = (unsigned)f2bf(la[2]) | ((unsigned)f2bf(la[3]) << 16);
            lo.z = (unsigned)f2bf(lb[0]) | ((unsigned)f2bf(lb[1]) << 16);
            lo.w = (unsigned)f2bf(lb[2]) | ((unsigned)f2bf(lb[3]) << 16);
            hi.x = (unsigned)f2bf(ha[0]) | ((unsigned)f2bf(ha[1]) << 16);
            hi.y = (unsigned)f2bf(ha[2]) | ((unsigned)f2bf(ha[3]) << 16);
            hi.z = (unsigned)f2bf(hb[0]) | ((unsigned)f2bf(hb[1]) << 16);
            hi.w = (unsigned)f2bf(hb[2]) | ((unsigned)f2bf(hb[3]) << 16);
            *(u32x4*)&dst[j0] = lo;
            *(u32x4*)&dst[64 + j0] = hi;
        } else {
            const int gmb = m0 + p * 32 + vsh * 16;
            const int bb = gmb >> 11, s0 = gmb & 2047;
            const int vh = (bx - 10) * 2 + (vd >> 7), dl = vd & 127;
            unsigned short* dst = Vt + ((long)(bb * NKV + vh) * HD + dl) * S_LEN + s0;
            unsigned short pv[16];
            #pragma unroll
            for (int t = 0; t < 16; ++t)
                pv[t] = f2bf(Ep[(vsh * 16 + t) * EPLD + vd]);
            u32x4 v0, v1;
            v0.x = (unsigned)pv[0]  | ((unsigned)pv[1]  << 16);
            v0.y = (unsigned)pv[2]  | ((unsigned)pv[3]  << 16);
            v0.z = (unsigned)pv[4]  | ((unsigned)pv[5]  << 16);
            v0.w = (unsigned)pv[6]  | ((unsigned)pv[7]  << 16);
            v1.x = (unsigned)pv[8]  | ((unsigned)pv[9]  << 16);
            v1.y = (unsigned)pv[10] | ((unsigned)pv[11] << 16);
            v1.z = (unsigned)pv[12] | ((unsigned)pv[13] << 16);
            v1.w = (unsigned)pv[14] | ((unsigned)pv[15] << 16);
            *(u32x4*)&dst[0] = v0;
            *(u32x4*)&dst[8] = v1;
        }
        __syncthreads();
    }
}

// ---------------------------------------------------------------------------
// GEMM2: d_out fp32 = AO bf16 x WoT^T.  BK=64 swizzled K-loop (R10, proven).
// ---------------------------------------------------------------------------
template <typename CT>
__global__ __launch_bounds__(256) void gemm_bt_async(
        const unsigned short* __restrict__ A,
        const unsigned short* __restrict__ Bt,
        CT* __restrict__ C,
        const float* __restrict__ bias,
        int K, int lda, int ldb, int ldc) {
    __shared__ __align__(16) unsigned short As[128 * 64];
    __shared__ __align__(16) unsigned short Bs[128 * 64];
    const int tid = threadIdx.x;
    const int wid = tid >> 6, lane = tid & 63, quad = lane >> 4, l16 = lane & 15;
    const int wr = wid >> 1, wc = wid & 1;
    const int m0 = blockIdx.y * 128, n0 = blockIdx.x * 128;
    const int l7 = l16 & 7;

    f32x4 acc[4][4];
    #pragma unroll
    for (int i = 0; i < 4; i++)
        #pragma unroll
        for (int j = 0; j < 4; j++)
            #pragma unroll
            for (int c = 0; c < 4; c++) acc[i][j][c] = 0.f;

    for (int k0 = 0; k0 < K; k0 += 64) {
        #pragma unroll
        for (int i = 0; i < 4; i++) {
            int c = tid + 256 * i;
            int row = c >> 3, loct = ((c & 7) ^ (row & 7)) * 8;
            gload_lds16(&A[(long)(m0 + row) * lda + k0 + loct], &As[c * 8]);
        }
        #pragma unroll
        for (int i = 0; i < 4; i++) {
            int c = tid + 256 * i;
            int row = c >> 3, loct = ((c & 7) ^ (row & 7)) * 8;
            gload_lds16(&Bt[(long)(n0 + row) * ldb + k0 + loct], &Bs[c * 8]);
        }
        __syncthreads();
        #pragma unroll
        for (int s = 0; s < 2; s++) {
            bf16x8 af[4], bfr[4];
            #pragma unroll
            for (int mi = 0; mi < 4; mi++)
                af[mi] = *(const bf16x8*)
                    &As[(wr * 64 + mi * 16 + l16) * 64 + (((s * 4 + quad) ^ l7)) * 8];
            #pragma unroll
            for (int ni = 0; ni < 4; ni++)
                bfr[ni] = *(const bf16x8*)
                    &Bs[(wc * 64 + ni * 16 + l16) * 64 + (((s * 4 + quad) ^ l7)) * 8];
            #pragma unroll
            for (int mi = 0; mi < 4; mi++)
                #pragma unroll
                for (int ni = 0; ni < 4; ni++)
                    acc[mi][ni] = __builtin_amdgcn_mfma_f32_16x16x32_bf16(
                        af[mi], bfr[ni], acc[mi][ni], 0, 0, 0);
        }
        __syncthreads();
    }

    #pragma unroll
    for (int mi = 0; mi < 4; mi++) {
        #pragma unroll
        for (int ni = 0; ni < 4; ni++) {
            int gn = n0 + wc * 64 + ni * 16 + l16;
            float bv_ = bias ? bias[gn] : 0.f;
            #pragma unroll
            for (int r = 0; r < 4; r++) {
                int gm = m0 + wr * 64 + mi * 16 + quad * 4 + r;
                float v = acc[mi][ni][r] + bv_;
                if constexpr (sizeof(CT) == 4) C[(long)gm * ldc + gn] = v;
                else                           C[(long)gm * ldc + gn] = f2bf(v);
            }
        }
    }
}

// ---------------------------------------------------------------------------
// Causal flash attention, GQA, transposed scores.
// R15: 4 waves x 32 q-rows (256 thr).  Each wave owns two 16-row m-subtiles;
// K/V fragments are read ONCE per wave and fed to both subtiles' MFMAs
// (LDS ops/block-chunk 304 -> 176).  Memory structure, Ps 68-stride layout,
// XCD remap (x%8=b*4+hk), work-paired y, T13 defer-max: identical to R13.
// ---------------------------------------------------------------------------
__global__ __launch_bounds__(256, 2) void attn_kernel(
        const unsigned short* __restrict__ Qr,
        const unsigned short* __restrict__ Kr,
        const unsigned short* __restrict__ Vt,
        unsigned short* __restrict__ Out) {
    __shared__ __align__(16) unsigned short Ks[64 * 128];
    __shared__ __align__(16) unsigned short Vs[128 * 64];
    __shared__ __align__(16) unsigned short Ps[8][16 * 68];

    const int x = blockIdx.x, y = blockIdx.y;
    const int hk = x & 3, b = (x >> 2) & 1;
    const int h  = ((x & 3) << 2) + (x >> 3);            // h>>2 == hk
    const int qt = (y < 8) ? y : 23 - y;                 // pairs sum to 23
    const int tid = threadIdx.x, w = tid >> 6, lane = tid & 63;
    const int quad = lane >> 4, l16 = lane & 15;
    const unsigned short* Qb = Qr + (long)((b * NH + h) * S_LEN) * HD;
    const unsigned short* Kb = Kr + (long)((b * NKV + hk) * S_LEN) * HD;
    const unsigned short* Vb = Vt + (long)((b * NKV + hk) * HD) * S_LEN;
    const int qw0 = qt * 128 + w * 32;                   // wave's 32 rows
    const float MASK_MIN = -3.0e38f;

    bf16x8 qf[2][4];
    #pragma unroll
    for (int m = 0; m < 2; m++)
        #pragma unroll
        for (int kc = 0; kc < 4; kc++)
            qf[m][kc] = *(const bf16x8*)
                &Qb[(long)(qw0 + m * 16 + l16) * HD + kc * 32 + quad * 8];

    f32x4 o[2][8];
    #pragma unroll
    for (int m = 0; m < 2; m++)
        #pragma unroll
        for (int db = 0; db < 8; db++)
            #pragma unroll
            for (int c = 0; c < 4; c++) o[m][db][c] = 0.f;
    float mr[2] = { MASK_MIN, MASK_MIN }, lr[2] = { 0.f, 0.f };

    const int nkt = 2 * qt + 2;
    for (int kt = 0; kt < nkt; kt++) {
        const int k0 = kt * 64;
        __syncthreads();
        #pragma unroll
        for (int i = 0; i < 4; i++) {                    // 256 thr x 4 slots
            const int s = tid + 256 * i;
            const int kR = s >> 4, kC = ((s & 15) ^ (kR & 15)) * 8;
            const int vR = s >> 3, vC = ((s & 7) ^ (vR & 7)) * 8;
            gload_lds16(&Kb[(long)(k0 + kR) * HD + kC], &Ks[s * 8]);
            gload_lds16(&Vb[(long)vR * S_LEN + k0 + vC], &Vs[s * 8]);
        }
        __syncthreads();

        if (k0 > qw0 + 31) continue;                     // wave fully masked

        f32x4 sc[2][4];
        #pragma unroll
        for (int m = 0; m < 2; m++)
            #pragma unroll
            for (int nb = 0; nb < 4; nb++)
                #pragma unroll
                for (int c = 0; c < 4; c++) sc[m][nb][c] = 0.f;

        #pragma unroll
        for (int nb = 0; nb < 4; nb++)
            #pragma unroll
            for (int kc = 0; kc < 4; kc++) {
                bf16x8 kf = *(const bf16x8*)             // shared across m
                    &Ks[(nb * 16 + l16) * 128 + (((kc * 4 + quad) ^ l16) * 8)];
                sc[0][nb] = __builtin_amdgcn_mfma_f32_16x16x32_bf16(kf, qf[0][kc], sc[0][nb], 0, 0, 0);
                sc[1][nb] = __builtin_amdgcn_mfma_f32_16x16x32_bf16(kf, qf[1][kc], sc[1][nb], 0, 0, 0);
            }

        #pragma unroll
        for (int m = 0; m < 2; m++) {
            const int qwm = qw0 + m * 16, qm = qwm + l16;
            if (k0 + 63 > qwm) {          // diagonal/above: mask (Q pre-scaled)
                #pragma unroll
                for (int nb = 0; nb < 4; nb++) {
                    int kvb = k0 + nb * 16 + quad * 4;
                    #pragma unroll
                    for (int r = 0; r < 4; r++)
                        sc[m][nb][r] = (kvb + r > qm) ? MASK_MIN : sc[m][nb][r];
                }
            }
            float tm = MASK_MIN;
            #pragma unroll
            for (int nb = 0; nb < 4; nb++)
                #pragma unroll
                for (int r = 0; r < 4; r++) tm = fmaxf(tm, sc[m][nb][r]);
            tm = fmaxf(tm, __shfl_xor(tm, 16));
            tm = fmaxf(tm, __shfl_xor(tm, 32));

            float mn = mr[m];
            if (__any(tm > mr[m] + 8.f)) {   // T13: rescale only on growth > 8
                mn = fmaxf(mr[m], tm);
                float alpha = exp2f(mr[m] - mn);
                mr[m] = mn;
                lr[m] *= alpha;
                #pragma unroll
                for (int db = 0; db < 8; db++)
                    #pragma unroll
                    for (int c = 0; c < 4; c++) o[m][db][c] *= alpha;
            }
            float rs = 0.f;
            #pragma unroll
            for (int nb = 0; nb < 4; nb++) {
                float pv0 = exp2f(sc[m][nb][0] - mn), pv1 = exp2f(sc[m][nb][1] - mn);
                float pv2 = exp2f(sc[m][nb][2] - mn), pv3 = exp2f(sc[m][nb][3] - mn);
                rs += (pv0 + pv1) + (pv2 + pv3);
                bf16x4 pk4 = { (__bf16)pv0, (__bf16)pv1, (__bf16)pv2, (__bf16)pv3 };
                *(bf16x4*)&Ps[w * 2 + m][l16 * 68 + nb * 16 + quad * 4] = pk4;
            }
            rs += __shfl_xor(rs, 16);
            rs += __shfl_xor(rs, 32);
            lr[m] += rs;
        }

        #pragma unroll
        for (int kk = 0; kk < 2; kk++) {
            bf16x8 pf0 = *(const bf16x8*)&Ps[w * 2 + 0][l16 * 68 + kk * 32 + quad * 8];
            bf16x8 pf1 = *(const bf16x8*)&Ps[w * 2 + 1][l16 * 68 + kk * 32 + quad * 8];
            #pragma unroll
            for (int db = 0; db < 8; db++) {
                bf16x8 vf = *(const bf16x8*)             // shared across m
                    &Vs[(db * 16 + l16) * 64 + (((kk * 4 + quad) ^ (l16 & 7)) * 8)];
                o[0][db] = __builtin_amdgcn_mfma_f32_16x16x32_bf16(vf, pf0, o[0][db], 0, 0, 0);
                o[1][db] = __builtin_amdgcn_mfma_f32_16x16x32_bf16(vf, pf1, o[1][db], 0, 0, 0);
            }
        }
    }

    #pragma unroll
    for (int m = 0; m < 2; m++) {
        float inv_l = 1.0f / lr[m];
        long obase = (long)(b * S_LEN + qw0 + m * 16 + l16) * 2048 + h * 128 + quad * 4;
        #pragma unroll
        for (int db = 0; db < 8; db++) {
            bf16x4 pk4 = { (__bf16)(o[m][db][0] * inv_l), (__bf16)(o[m][db][1] * inv_l),
                           (__bf16)(o[m][db][2] * inv_l), (__bf16)(o[m][db][3] * inv_l) };
            *(bf16x4*)&Out[obase + db * 16] = pk4;
        }
    }
}

// ---------------------------------------------------------------------------
extern "C" void kernel_launch(void* const* d_in, const int* in_sizes, int n_in,
                              void* d_out, int out_size, void* d_ws, size_t ws_size,
                              hipStream_t stream) {
    const float* X  = (const float*)d_in[0];
    const float* tv = (const float*)d_in[1];
    const float* wq = (const float*)d_in[2];
    const float* bq = (const float*)d_in[3];
    const float* wk = (const float*)d_in[4];
    const float* bk = (const float*)d_in[5];
    const float* wv = (const float*)d_in[6];
    const float* bv = (const float*)d_in[7];
    const float* wo = (const float*)d_in[8];
    const float* rw = (const float*)d_in[9];

    // Workspace (~56 MB):
    //   Wt 12.6MB ([wq|wk|wv]^T -> reused for wo^T after gemm1)
    //   bsf 12KB, Tab 1MB, Qr 16.8MB, Kr/Vt 8.4MB, AO 16.8MB (=Xb alias)
    char* ws = (char*)d_ws;
    unsigned short* Wt  = (unsigned short*)ws; ws += 3072L * 2048 * 2;
    float*          bsf = (float*)ws;          ws += 3072L * 4;
    unsigned int*   Tab = (unsigned int*)ws;   ws += 4096L * 64 * 4;
    unsigned short* Qr  = (unsigned short*)ws; ws += (long)BATCH * NH  * S_LEN * HD * 2;
    unsigned short* Kr  = (unsigned short*)ws; ws += (long)BATCH * NKV * S_LEN * HD * 2;
    unsigned short* Vt  = (unsigned short*)ws; ws += (long)BATCH * NKV * HD * S_LEN * 2;
    unsigned short* AO  = (unsigned short*)ws; ws += 4096L * 2048 * 2;
    unsigned short* Xb  = AO;   // alias: Xb dead (post-gemm1) before attn writes AO

    transpose_qkv<<<dim3(64, 64, 3), dim3(32, 8), 0, stream>>>(wq, wk, wv, Wt);
    prep_kernel<<<4096, 256, 0, stream>>>(X, Xb, bq, bk, bv, bsf, tv, rw, Tab);
    gemm_qkv_rope<<<dim3(12, 16), 512, 0, stream>>>(Xb, Wt, bsf, Tab, Qr, Kr, Vt);
    transpose_to_bf16<<<dim3(64, 64), dim3(32, 8), 0, stream>>>(wo, Wt, 2048, 2048, 0L, 2048);
    attn_kernel<<<dim3(32, 16, 1), 256, 0, stream>>>(Qr, Kr, Vt, AO);
    gemm_bt_async<float><<<dim3(16, 32), 256, 0, stream>>>(
        AO, Wt, (float*)d_out, nullptr, 2048, 2048, 2048, 2048);
}

// Round 6
// 301.320 us; speedup vs baseline: 1.0236x; 1.0236x over previous
//
#include <hip/hip_runtime.h>

// ---------------------------------------------------------------------------
// TimeMoeAttention: X@Wq/Wk/Wv + bias -> continuous-time RoPE -> causal GQA
// attention -> @Wo.  B=2, S=2048, H=2048, NH=16, NKV=4, HD=128.
// I/O fp32; internal bf16 + fp32 MFMA accumulation.
// R16: attn reverted to R13 exactly (73.7us proven; R14/R15 structural
//      variants both regressed via occupancy loss).  gemm2 ported to a
//      full-machine 4-phase pipelined schedule: 128x256 tiles -> 256 blocks
//      (R12's 256^2 failure was 128 blocks = half machine idle), 8 waves
//      2Mx4N (wave-tile 64x64, acc[4][4], 16 MFMA/phase), A slot 128x32
//      (1 gload/thr) + B slot 256x32 (2 gloads/thr), 96KiB LDS, uniform
//      vmcnt(6) per phase (FIFO: 3-gload batches, slot read 3 phases after
//      stage; derivation in comments).  XCD swizzle: same-XCD blocks share
//      one 1MB B-panel.
// ---------------------------------------------------------------------------

#define S_LEN 2048
#define BATCH 2
#define NH    16
#define NKV   4
#define HD    128

typedef float  f32x4  __attribute__((ext_vector_type(4)));
typedef __bf16 bf16x8 __attribute__((ext_vector_type(8)));
typedef __bf16 bf16x4 __attribute__((ext_vector_type(4)));
typedef unsigned int u32x4 __attribute__((ext_vector_type(4)));
typedef unsigned int u32x2 __attribute__((ext_vector_type(2)));

__device__ inline unsigned short f2bf(float f) {
    unsigned u = __builtin_bit_cast(unsigned, f);
    unsigned r = (u + 0x7fffu + ((u >> 16) & 1u)) >> 16;   // RNE
    return (unsigned short)r;
}

// async global->LDS, 16 bytes per lane (dest = wave-uniform base + lane*16)
__device__ inline void gload_lds16(const void* g, void* l) {
    __builtin_amdgcn_global_load_lds(
        (const __attribute__((address_space(1))) unsigned int*)g,
        (__attribute__((address_space(3))) unsigned int*)l, 16, 0, 0);
}

// ---------------------------------------------------------------------------
// Fused transposes: wq|wk|wv (fp32) -> Wt (bf16, [3072][2048]).  z selects.
// ---------------------------------------------------------------------------
__global__ void transpose_qkv(const float* __restrict__ wq,
                              const float* __restrict__ wk,
                              const float* __restrict__ wv,
                              unsigned short* __restrict__ Wt) {
    int z = blockIdx.z;
    const float* src = (z == 0) ? wq : ((z == 1) ? wk : wv);
    int C = (z == 0) ? 2048 : 512;
    long doff = (z == 0) ? 0L : ((z == 1) ? 2048L * 2048 : 2560L * 2048);
    int bx = blockIdx.x * 32, by = blockIdx.y * 32;
    if (bx >= C) return;
    __shared__ unsigned short t[32][33];
    int x = threadIdx.x, y0 = threadIdx.y;
    #pragma unroll
    for (int i = 0; i < 4; i++) {
        int y = y0 + i * 8;
        t[y][x] = f2bf(src[(long)(by + y) * C + bx + x]);
    }
    __syncthreads();
    #pragma unroll
    for (int i = 0; i < 4; i++) {
        int y = y0 + i * 8;
        Wt[doff + (long)(bx + y) * 2048 + by + x] = t[x][y];
    }
}

// single fp32->bf16 transpose (for wo, launched after gemm1 frees Wt)
__global__ void transpose_to_bf16(const float* __restrict__ src,
                                  unsigned short* __restrict__ dst,
                                  int R, int C, long dst_off, int ldd) {
    __shared__ unsigned short t[32][33];
    int bx = blockIdx.x * 32, by = blockIdx.y * 32;
    int x = threadIdx.x, y0 = threadIdx.y;
    #pragma unroll
    for (int i = 0; i < 4; i++) {
        int y = y0 + i * 8;
        t[y][x] = f2bf(src[(long)(by + y) * C + bx + x]);
    }
    __syncthreads();
    #pragma unroll
    for (int i = 0; i < 4; i++) {
        int y = y0 + i * 8;
        dst[dst_off + (long)(bx + y) * ldd + by + x] = t[x][y];
    }
}

// ---------------------------------------------------------------------------
// Prep: X fp32->bf16 (all 4096 blocks), bias concat (blocks 0-11),
// rope table Tab[4096 tokens][64 freqs x (cs,sn) bf16 pairs] (blocks 0-1023).
// ---------------------------------------------------------------------------
__global__ __launch_bounds__(256) void prep_kernel(
        const float* __restrict__ X, unsigned short* __restrict__ Xb,
        const float* __restrict__ bq, const float* __restrict__ bk,
        const float* __restrict__ bv, float* __restrict__ bsf,
        const float* __restrict__ tv, const float* __restrict__ rw,
        unsigned int* __restrict__ Tab) {
    int bi = blockIdx.x, tid = threadIdx.x;
    long i = ((long)bi * 256 + tid) * 8;
    {
        f32x4 a = *(const f32x4*)&X[i];
        f32x4 b = *(const f32x4*)&X[i + 4];
        u32x4 r;
        r.x = (unsigned)f2bf(a[0]) | ((unsigned)f2bf(a[1]) << 16);
        r.y = (unsigned)f2bf(a[2]) | ((unsigned)f2bf(a[3]) << 16);
        r.z = (unsigned)f2bf(b[0]) | ((unsigned)f2bf(b[1]) << 16);
        r.w = (unsigned)f2bf(b[2]) | ((unsigned)f2bf(b[3]) << 16);
        *(u32x4*)&Xb[i] = r;
    }
    if (bi < 12) {
        int ib = bi * 256 + tid;
        bsf[ib] = (ib < 2048) ? bq[ib] : ((ib < 2560) ? bk[ib - 2048] : bv[ib - 2560]);
    }
    if (bi < 1024) {
        int m = bi * 4 + (tid >> 6);
        int fi = tid & 63;
        float t = tv[m];
        float f = t * powf(10000.f, -(float)fi / 64.f) * rw[fi];
        Tab[m * 64 + fi] = (unsigned)f2bf(cosf(f)) | ((unsigned)f2bf(sinf(f)) << 16);
    }
}

// ---------------------------------------------------------------------------
// 256x256 8-phase GEMM machinery (R11; proven).  LDS slots: A(buf,ks) at
// buf*16384+ks*8192, B at +32768.  Slot=256rx32k, XOR-swizzled
// kgrp^((row>>1)&3).  Staging: linear LDS dest + pre-swizzled global col.
// vmcnt(6) at phases 4/8 only.
// ---------------------------------------------------------------------------
__device__ __forceinline__ void stage_half(const unsigned short* __restrict__ G,
        int baseRow, long kc, unsigned short* slot, int r0, int c0, int tid) {
    gload_lds16(&G[(long)(baseRow + r0) * 2048 + kc + c0], &slot[tid * 8]);
    gload_lds16(&G[(long)(baseRow + r0 + 128) * 2048 + kc + c0], &slot[4096 + tid * 8]);
}

#define STG_A(buf, ks, kt) \
    stage_half(A,  m0, (long)(kt) * 64 + (ks) * 32, &sm[(buf) * 16384 + (ks) * 8192], r0s, c0s, tid)
#define STG_B(buf, ks, kt) \
    stage_half(Bt, n0, (long)(kt) * 64 + (ks) * 32, &sm[32768 + (buf) * 16384 + (ks) * 8192], r0s, c0s, tid)

#define NOPV ((void)0)
#define VM6  asm volatile("s_waitcnt vmcnt(6)" ::: "memory")

#define PH(buf, ks, mh, RDB, STG, VM)                                          \
    {                                                                          \
        const int sb_ = (buf) * 16384 + (ks) * 8192;                           \
        bf16x8 a0 = *(const bf16x8*)&sm[sb_ + abase + (mh) * 2048];            \
        bf16x8 a1 = *(const bf16x8*)&sm[sb_ + abase + (mh) * 2048 + 512];      \
        bf16x8 a2 = *(const bf16x8*)&sm[sb_ + abase + (mh) * 2048 + 1024];     \
        bf16x8 a3 = *(const bf16x8*)&sm[sb_ + abase + (mh) * 2048 + 1536];     \
        if (RDB) {                                                             \
            b0 = *(const bf16x8*)&sm[sb_ + bbase];                             \
            b1 = *(const bf16x8*)&sm[sb_ + bbase + 512];                       \
            b2 = *(const bf16x8*)&sm[sb_ + bbase + 1024];                      \
            b3 = *(const bf16x8*)&sm[sb_ + bbase + 1536];                      \
        }                                                                      \
        STG;                                                                   \
        VM;                                                                    \
        __builtin_amdgcn_s_barrier();                                          \
        asm volatile("s_waitcnt lgkmcnt(0)" ::: "memory");                     \
        __builtin_amdgcn_sched_barrier(0);                                     \
        __builtin_amdgcn_s_setprio(1);                                         \
        _Pragma("unroll") for (int mi = 0; mi < 4; ++mi) {                     \
            bf16x8 am = (mi == 0) ? a0 : (mi == 1) ? a1 : (mi == 2) ? a2 : a3; \
            acc[(mh) * 4 + mi][0] = __builtin_amdgcn_mfma_f32_16x16x32_bf16(   \
                am, b0, acc[(mh) * 4 + mi][0], 0, 0, 0);                       \
            acc[(mh) * 4 + mi][1] = __builtin_amdgcn_mfma_f32_16x16x32_bf16(   \
                am, b1, acc[(mh) * 4 + mi][1], 0, 0, 0);                       \
            acc[(mh) * 4 + mi][2] = __builtin_amdgcn_mfma_f32_16x16x32_bf16(   \
                am, b2, acc[(mh) * 4 + mi][2], 0, 0, 0);                       \
            acc[(mh) * 4 + mi][3] = __builtin_amdgcn_mfma_f32_16x16x32_bf16(   \
                am, b3, acc[(mh) * 4 + mi][3], 0, 0, 0);                       \
        }                                                                      \
        __builtin_amdgcn_s_setprio(0);                                         \
        __builtin_amdgcn_s_barrier();                                          \
    }

#define GEMM_PRO_LOOP(NIT)                                                     \
    STG_B(0, 0, 0); STG_A(0, 0, 0); STG_B(0, 1, 0); STG_A(0, 1, 0);            \
    STG_B(1, 0, 1); STG_A(1, 0, 1); STG_B(1, 1, 1);                            \
    asm volatile("s_waitcnt vmcnt(6)" ::: "memory");                           \
    __builtin_amdgcn_s_barrier();                                              \
    for (int it = 0; it < (NIT); ++it) {                                       \
        const int t1  = 2 * it + 1;                                            \
        const int tn0 = (it < (NIT) - 1) ? 2 * it + 2 : 2 * (NIT) - 1;         \
        const int tn1 = (it < (NIT) - 1) ? 2 * it + 3 : 2 * (NIT) - 1;         \
        PH(0, 0, 0, 1, STG_A(1, 1, t1),  NOPV);                                \
        PH(0, 0, 1, 0, STG_B(0, 0, tn0), NOPV);                                \
        PH(0, 1, 0, 1, STG_A(0, 0, tn0), NOPV);                                \
        PH(0, 1, 1, 0, STG_B(0, 1, tn0), VM6);                                 \
        PH(1, 0, 0, 1, STG_A(0, 1, tn0), NOPV);                                \
        PH(1, 0, 1, 0, STG_B(1, 0, tn1), NOPV);                                \
        PH(1, 1, 0, 1, STG_A(1, 0, tn1), NOPV);                                \
        PH(1, 1, 1, 0, STG_B(1, 1, tn1), VM6);                                 \
    }

// ---------------------------------------------------------------------------
// GEMM1 + bias + RoPE fused, 256x256 8-phase schedule (R11).
// Grid (12,16): bx 0..7 -> Q heads 2bx,2bx+1; 8,9 -> K; 10,11 -> V.
// ---------------------------------------------------------------------------
__global__ __launch_bounds__(512, 2) void gemm_qkv_rope(
        const unsigned short* __restrict__ A,
        const unsigned short* __restrict__ Bt,
        const float* __restrict__ bsf,
        const unsigned int* __restrict__ Tab,
        unsigned short* __restrict__ Qr,
        unsigned short* __restrict__ Kr,
        unsigned short* __restrict__ Vt) {
    __shared__ __align__(16) unsigned short sm[65536];   // 128 KiB

    const int tid = threadIdx.x;
    const int wid = tid >> 6, lane = tid & 63, quad = lane >> 4, l16 = lane & 15;
    const int wr = wid >> 2, wc = wid & 3;               // 2M x 4N waves

    // XCD-aware bijective swizzle (192 blocks, 192 % 8 == 0)
    const int u   = blockIdx.y * 12 + blockIdx.x;
    const int swz = (u & 7) * 24 + (u >> 3);
    const int bx  = swz % 12;
    const int m0  = (swz / 12) * 256;
    const int n0  = bx * 256;

    // fragment-read addressing (XOR bank swizzle on the k-group)
    const int sg    = (quad ^ ((l16 >> 1) & 3)) * 8;
    const int abase = wr * 4096 + l16 * 32 + sg;
    const int bbase = 32768 + wc * 2048 + l16 * 32 + sg;

    // staging addressing: linear LDS dest, pre-swizzled global column
    const int r0s = tid >> 2;
    const int c0s = ((tid & 3) ^ ((r0s >> 1) & 3)) * 8;

    f32x4 acc[8][4];
    #pragma unroll
    for (int i = 0; i < 8; i++)
        #pragma unroll
        for (int j = 0; j < 4; j++)
            #pragma unroll
            for (int c = 0; c < 4; c++) acc[i][j][c] = 0.f;
    bf16x8 b0 = {}, b1 = {}, b2 = {}, b3 = {};

    GEMM_PRO_LOOP(16)

    // drain stray prefetches before reusing smem for the epilogue
    asm volatile("s_waitcnt vmcnt(0)" ::: "memory");
    __syncthreads();

    // ---- fused epilogue: bias + RoPE (Q,K) / transpose (V), 8x32 tokens ----
    float* Ep = (float*)sm;
    const int EPLD = 264;                                // 256 + 8 pad
    float bv4[4];
    #pragma unroll
    for (int ni = 0; ni < 4; ++ni) bv4[ni] = bsf[n0 + wc * 64 + ni * 16 + l16];
    const bool isV = (bx >= 10);
    const float qs = (bx < 8) ? (0.08838834764831845f * 1.4426950408889634f) : 1.0f;

    const int lt = tid >> 4, hh = (tid >> 3) & 1, jj = tid & 7, j0 = jj * 8;
    const int vd = tid >> 1, vsh = tid & 1;

    #pragma unroll
    for (int p = 0; p < 8; ++p) {
        if (wr == (p >> 2)) {
            #pragma unroll
            for (int f = 0; f < 2; ++f) {
                #pragma unroll
                for (int ni = 0; ni < 4; ++ni)
                    #pragma unroll
                    for (int r = 0; r < 4; ++r)
                        Ep[(f * 16 + quad * 4 + r) * EPLD + wc * 64 + ni * 16 + l16] =
                            acc[(p & 3) * 2 + f][ni][r] + bv4[ni];
            }
        }
        __syncthreads();
        if (!isV) {
            const int gm = m0 + p * 32 + lt;
            const int bb = gm >> 11, s = gm & 2047;
            unsigned short* dst = (bx < 8)
                ? Qr + ((long)(bb * NH + bx * 2 + hh) * S_LEN + s) * HD
                : Kr + ((long)(bb * NKV + (bx - 8) * 2 + hh) * S_LEN + s) * HD;
            u32x4 t0 = *(const u32x4*)&Tab[(long)gm * 64 + j0];
            u32x4 t1v = *(const u32x4*)&Tab[(long)gm * 64 + j0 + 4];
            f32x4 x1a = *(f32x4*)&Ep[lt * EPLD + hh * 128 + j0];
            f32x4 x1b = *(f32x4*)&Ep[lt * EPLD + hh * 128 + j0 + 4];
            f32x4 x2a = *(f32x4*)&Ep[lt * EPLD + hh * 128 + 64 + j0];
            f32x4 x2b = *(f32x4*)&Ep[lt * EPLD + hh * 128 + 64 + j0 + 4];
            f32x4 la, lb, ha, hb;
            #pragma unroll
            for (int e = 0; e < 4; e++) {
                float ca = __builtin_bit_cast(float, t0[e] << 16);
                float sa = __builtin_bit_cast(float, t0[e] & 0xffff0000u);
                float cb = __builtin_bit_cast(float, t1v[e] << 16);
                float sbv = __builtin_bit_cast(float, t1v[e] & 0xffff0000u);
                la[e] = (x1a[e] * ca - x2a[e] * sa) * qs;
                ha[e] = (x2a[e] * ca + x1a[e] * sa) * qs;
                lb[e] = (x1b[e] * cb - x2b[e] * sbv) * qs;
                hb[e] = (x2b[e] * cb + x1b[e] * sbv) * qs;
            }
            u32x4 lo, hi;
            lo.x = (unsigned)f2bf(la[0]) | ((unsigned)f2bf(la[1]) << 16);
            lo.y = (unsigned)f2bf(la[2]) | ((unsigned)f2bf(la[3]) << 16);
            lo.z = (unsigned)f2bf(lb[0]) | ((unsigned)f2bf(lb[1]) << 16);
            lo.w = (unsigned)f2bf(lb[2]) | ((unsigned)f2bf(lb[3]) << 16);
            hi.x = (unsigned)f2bf(ha[0]) | ((unsigned)f2bf(ha[1]) << 16);
            hi.y = (unsigned)f2bf(ha[2]) | ((unsigned)f2bf(ha[3]) << 16);
            hi.z = (unsigned)f2bf(hb[0]) | ((unsigned)f2bf(hb[1]) << 16);
            hi.w = (unsigned)f2bf(hb[2]) | ((unsigned)f2bf(hb[3]) << 16);
            *(u32x4*)&dst[j0] = lo;
            *(u32x4*)&dst[64 + j0] = hi;
        } else {
            const int gmb = m0 + p * 32 + vsh * 16;
            const int bb = gmb >> 11, s0 = gmb & 2047;
            const int vh = (bx - 10) * 2 + (vd >> 7), dl = vd & 127;
            unsigned short* dst = Vt + ((long)(bb * NKV + vh) * HD + dl) * S_LEN + s0;
            unsigned short pv[16];
            #pragma unroll
            for (int t = 0; t < 16; ++t)
                pv[t] = f2bf(Ep[(vsh * 16 + t) * EPLD + vd]);
            u32x4 v0, v1;
            v0.x = (unsigned)pv[0]  | ((unsigned)pv[1]  << 16);
            v0.y = (unsigned)pv[2]  | ((unsigned)pv[3]  << 16);
            v0.z = (unsigned)pv[4]  | ((unsigned)pv[5]  << 16);
            v0.w = (unsigned)pv[6]  | ((unsigned)pv[7]  << 16);
            v1.x = (unsigned)pv[8]  | ((unsigned)pv[9]  << 16);
            v1.y = (unsigned)pv[10] | ((unsigned)pv[11] << 16);
            v1.z = (unsigned)pv[12] | ((unsigned)pv[13] << 16);
            v1.w = (unsigned)pv[14] | ((unsigned)pv[15] << 16);
            *(u32x4*)&dst[0] = v0;
            *(u32x4*)&dst[8] = v1;
        }
        __syncthreads();
    }
}

// ---------------------------------------------------------------------------
// GEMM2 (R16): d_out fp32 = AO bf16 [4096][2048] x Wt(wo^T) [2048][2048]^T.
// 128x256 tiles -> grid 256 blocks (1/CU).  8 waves 2Mx4N, wave-tile 64x64,
// acc[4][4], 16 MFMA per phase.  LDS 96KiB:
//   A slots (buf*2+ks)*4096  [128 rows x 32 k, 1 gload/thr]
//   B slots 16384+(buf*2+ks)*8192 [256 rows x 32 k, 2 gloads/thr]
// 4 phases per iteration (2 K-tiles).  Stage-after-read schedule:
//   ph1 rd(0,0) stg(1,1)<-t1 | ph2 rd(0,1) stg(0,0)<-tn0
//   ph3 rd(1,0) stg(0,1)<-tn0 | ph4 rd(1,1) stg(1,0)<-tn1
// Slot read 3 phases after stage; batches = 3 gloads -> vmcnt(6) at EVERY
// phase guarantees the batch staged 3 phases ago landed before next read.
// ---------------------------------------------------------------------------
#define OSTG_A(buf, ks, kt)                                                    \
    gload_lds16(&A[(long)(m0 + r0s) * 2048 + (kt) * 64 + (ks) * 32 + c0s],     \
                &sm[((buf) * 2 + (ks)) * 4096 + tid * 8])
#define OSTG_B(buf, ks, kt)                                                    \
    stage_half(Bt, n0, (long)(kt) * 64 + (ks) * 32,                            \
               &sm[16384 + ((buf) * 2 + (ks)) * 8192], r0s, c0s, tid)

#define OPH(buf, ks, STG)                                                      \
    {                                                                          \
        const int ab_ = ((buf) * 2 + (ks)) * 4096 + abase;                     \
        const int bb_ = ((buf) * 2 + (ks)) * 8192 + bbase;                     \
        bf16x8 a0 = *(const bf16x8*)&sm[ab_];                                  \
        bf16x8 a1 = *(const bf16x8*)&sm[ab_ + 512];                            \
        bf16x8 a2 = *(const bf16x8*)&sm[ab_ + 1024];                           \
        bf16x8 a3 = *(const bf16x8*)&sm[ab_ + 1536];                           \
        bf16x8 b0 = *(const bf16x8*)&sm[bb_];                                  \
        bf16x8 b1 = *(const bf16x8*)&sm[bb_ + 512];                            \
        bf16x8 b2 = *(const bf16x8*)&sm[bb_ + 1024];                           \
        bf16x8 b3 = *(const bf16x8*)&sm[bb_ + 1536];                           \
        STG;                                                                   \
        asm volatile("s_waitcnt vmcnt(6)" ::: "memory");                       \
        __builtin_amdgcn_s_barrier();                                          \
        asm volatile("s_waitcnt lgkmcnt(0)" ::: "memory");                     \
        __builtin_amdgcn_sched_barrier(0);                                     \
        __builtin_amdgcn_s_setprio(1);                                         \
        _Pragma("unroll") for (int mi = 0; mi < 4; ++mi) {                     \
            bf16x8 am = (mi == 0) ? a0 : (mi == 1) ? a1 : (mi == 2) ? a2 : a3; \
            acc[mi][0] = __builtin_amdgcn_mfma_f32_16x16x32_bf16(              \
                am, b0, acc[mi][0], 0, 0, 0);                                  \
            acc[mi][1] = __builtin_amdgcn_mfma_f32_16x16x32_bf16(              \
                am, b1, acc[mi][1], 0, 0, 0);                                  \
            acc[mi][2] = __builtin_amdgcn_mfma_f32_16x16x32_bf16(              \
                am, b2, acc[mi][2], 0, 0, 0);                                  \
            acc[mi][3] = __builtin_amdgcn_mfma_f32_16x16x32_bf16(              \
                am, b3, acc[mi][3], 0, 0, 0);                                  \
        }                                                                      \
        __builtin_amdgcn_s_setprio(0);                                         \
        __builtin_amdgcn_s_barrier();                                          \
    }

__global__ __launch_bounds__(512, 2) void gemm_o(
        const unsigned short* __restrict__ A,
        const unsigned short* __restrict__ Bt,
        float* __restrict__ C) {
    __shared__ __align__(16) unsigned short sm[49152];   // 96 KiB

    const int tid = threadIdx.x;
    const int wid = tid >> 6, lane = tid & 63, quad = lane >> 4, l16 = lane & 15;
    const int wr = wid >> 2, wc = wid & 3;               // 2M x 4N, tile 64x64

    // XCD swizzle: grid (8,32) = 256 blocks; same-XCD blocks share n-tile
    const int u   = blockIdx.y * 8 + blockIdx.x;
    const int swz = (u & 7) * 32 + (u >> 3);
    const int m0  = (swz & 31) * 128;
    const int n0  = (swz >> 5) * 256;

    const int sg    = (quad ^ ((l16 >> 1) & 3)) * 8;
    const int abase = (wr * 64 + l16) * 32 + sg;
    const int bbase = 16384 + (wc * 64 + l16) * 32 + sg;
    const int r0s = tid >> 2;
    const int c0s = ((tid & 3) ^ ((r0s >> 1) & 3)) * 8;

    f32x4 acc[4][4];
    #pragma unroll
    for (int i = 0; i < 4; i++)
        #pragma unroll
        for (int j = 0; j < 4; j++)
            #pragma unroll
            for (int c = 0; c < 4; c++) acc[i][j][c] = 0.f;

    // prologue: tile0 full + tile1 partial (A10,B10); first batch = A00+B00
    OSTG_A(0, 0, 0); OSTG_B(0, 0, 0);
    OSTG_A(0, 1, 0); OSTG_B(0, 1, 0);
    OSTG_A(1, 0, 1); OSTG_B(1, 0, 1);
    asm volatile("s_waitcnt vmcnt(6)" ::: "memory");     // A00,B00 landed
    __builtin_amdgcn_s_barrier();

    for (int it = 0; it < 16; ++it) {
        const int t1  = 2 * it + 1;
        const int tn0 = (it < 15) ? 2 * it + 2 : 31;     // tail: reload, unread
        const int tn1 = (it < 15) ? 2 * it + 3 : 31;
        OPH(0, 0, OSTG_A(1, 1, t1);  OSTG_B(1, 1, t1))
        OPH(0, 1, OSTG_A(0, 0, tn0); OSTG_B(0, 0, tn0))
        OPH(1, 0, OSTG_A(0, 1, tn0); OSTG_B(0, 1, tn0))
        OPH(1, 1, OSTG_A(1, 0, tn1); OSTG_B(1, 0, tn1))
    }

    asm volatile("s_waitcnt vmcnt(0)" ::: "memory");     // drain tail prefetch

    #pragma unroll
    for (int mi = 0; mi < 4; mi++)
        #pragma unroll
        for (int ni = 0; ni < 4; ni++) {
            const int gn = n0 + wc * 64 + ni * 16 + l16;
            #pragma unroll
            for (int r = 0; r < 4; r++) {
                const int gm = m0 + wr * 64 + mi * 16 + quad * 4 + r;
                C[(long)gm * 2048 + gn] = acc[mi][ni][r];
            }
        }
}

// ---------------------------------------------------------------------------
// Causal flash attention, GQA, transposed scores (R13, proven 73.7us).
// Grid (32,16): x%8 = b*4+hk -> 64 blocks sharing one 2MB KV stream land on
// one XCD's L2.  qt = y<8?y:23-y balances intra-XCD pairs (sum 23).
// T13 defer-max: skip O-rescale while tile max grows <= 8 (log2 domain).
// ---------------------------------------------------------------------------
__global__ __launch_bounds__(512, 4) void attn_kernel(
        const unsigned short* __restrict__ Qr,
        const unsigned short* __restrict__ Kr,
        const unsigned short* __restrict__ Vt,
        unsigned short* __restrict__ Out) {
    __shared__ __align__(16) unsigned short Ks[64 * 128];
    __shared__ __align__(16) unsigned short Vs[128 * 64];
    __shared__ __align__(16) unsigned short Ps[8][16 * 68];

    const int x = blockIdx.x, y = blockIdx.y;
    const int hk = x & 3, b = (x >> 2) & 1;
    const int h  = ((x & 3) << 2) + (x >> 3);            // h>>2 == hk
    const int qt = (y < 8) ? y : 23 - y;                 // pairs sum to 23
    const int tid = threadIdx.x, w = tid >> 6, lane = tid & 63;
    const int quad = lane >> 4, l16 = lane & 15;
    const unsigned short* Qb = Qr + (long)((b * NH + h) * S_LEN) * HD;
    const unsigned short* Kb = Kr + (long)((b * NKV + hk) * S_LEN) * HD;
    const unsigned short* Vb = Vt + (long)((b * NKV + hk) * HD) * S_LEN;
    const int qw = qt * 128 + w * 16;
    const int q  = qw + l16;
    const float MASK_MIN = -3.0e38f;

    bf16x8 qf[4];
    #pragma unroll
    for (int kc = 0; kc < 4; kc++)
        qf[kc] = *(const bf16x8*)&Qb[(long)q * HD + kc * 32 + quad * 8];

    f32x4 o[8];
    #pragma unroll
    for (int db = 0; db < 8; db++)
        #pragma unroll
        for (int c = 0; c < 4; c++) o[db][c] = 0.f;
    float mr = MASK_MIN, lr = 0.f;

    const int sK0 = tid, sK1 = tid + 512;
    const int kR0 = sK0 >> 4, kC0 = ((sK0 & 15) ^ (kR0 & 15)) * 8;
    const int kR1 = sK1 >> 4, kC1 = ((sK1 & 15) ^ (kR1 & 15)) * 8;
    const int vR0 = sK0 >> 3, vC0 = ((sK0 & 7) ^ (vR0 & 7)) * 8;
    const int vR1 = sK1 >> 3, vC1 = ((sK1 & 7) ^ (vR1 & 7)) * 8;

    const int nkt = 2 * qt + 2;
    for (int kt = 0; kt < nkt; kt++) {
        const int k0 = kt * 64;
        __syncthreads();
        gload_lds16(&Kb[(long)(k0 + kR0) * HD + kC0], &Ks[sK0 * 8]);
        gload_lds16(&Kb[(long)(k0 + kR1) * HD + kC1], &Ks[sK1 * 8]);
        gload_lds16(&Vb[(long)vR0 * S_LEN + k0 + vC0], &Vs[sK0 * 8]);
        gload_lds16(&Vb[(long)vR1 * S_LEN + k0 + vC1], &Vs[sK1 * 8]);
        __syncthreads();

        if (k0 > qw + 15) continue;

        f32x4 sc[4];
        #pragma unroll
        for (int nb = 0; nb < 4; nb++) {
            #pragma unroll
            for (int c = 0; c < 4; c++) sc[nb][c] = 0.f;
            #pragma unroll
            for (int kc = 0; kc < 4; kc++) {
                bf16x8 kf = *(const bf16x8*)
                    &Ks[(nb * 16 + l16) * 128 + (((kc * 4 + quad) ^ l16) * 8)];
                sc[nb] = __builtin_amdgcn_mfma_f32_16x16x32_bf16(kf, qf[kc], sc[nb], 0, 0, 0);
            }
        }
        if (k0 + 63 > qw) {   // diagonal tile: mask only (Q pre-scaled)
            #pragma unroll
            for (int nb = 0; nb < 4; nb++) {
                int kvb = k0 + nb * 16 + quad * 4;
                #pragma unroll
                for (int r = 0; r < 4; r++)
                    sc[nb][r] = (kvb + r > q) ? MASK_MIN : sc[nb][r];
            }
        }
        float tm = MASK_MIN;
        #pragma unroll
        for (int nb = 0; nb < 4; nb++)
            #pragma unroll
            for (int r = 0; r < 4; r++) tm = fmaxf(tm, sc[nb][r]);
        tm = fmaxf(tm, __shfl_xor(tm, 16));
        tm = fmaxf(tm, __shfl_xor(tm, 32));

        float mn = mr;
        if (__any(tm > mr + 8.f)) {         // T13: rescale only on growth > 8
            mn = fmaxf(mr, tm);
            float alpha = exp2f(mr - mn);
            mr = mn;
            lr *= alpha;
            #pragma unroll
            for (int db = 0; db < 8; db++)
                #pragma unroll
                for (int c = 0; c < 4; c++) o[db][c] *= alpha;
        }
        float rs = 0.f;
        #pragma unroll
        for (int nb = 0; nb < 4; nb++) {
            float pv0 = exp2f(sc[nb][0] - mn), pv1 = exp2f(sc[nb][1] - mn);
            float pv2 = exp2f(sc[nb][2] - mn), pv3 = exp2f(sc[nb][3] - mn);
            rs += (pv0 + pv1) + (pv2 + pv3);
            bf16x4 pk4 = { (__bf16)pv0, (__bf16)pv1, (__bf16)pv2, (__bf16)pv3 };
            *(bf16x4*)&Ps[w][l16 * 68 + nb * 16 + quad * 4] = pk4;
        }
        rs += __shfl_xor(rs, 16);
        rs += __shfl_xor(rs, 32);
        lr += rs;

        #pragma unroll
        for (int kk = 0; kk < 2; kk++) {
            bf16x8 pf = *(const bf16x8*)&Ps[w][l16 * 68 + kk * 32 + quad * 8];
            #pragma unroll
            for (int db = 0; db < 8; db++) {
                bf16x8 vf = *(const bf16x8*)
                    &Vs[(db * 16 + l16) * 64 + (((kk * 4 + quad) ^ (l16 & 7)) * 8)];
                o[db] = __builtin_amdgcn_mfma_f32_16x16x32_bf16(vf, pf, o[db], 0, 0, 0);
            }
        }
    }

    float inv_l = 1.0f / lr;
    long obase = (long)(b * S_LEN + q) * 2048 + h * 128 + quad * 4;
    #pragma unroll
    for (int db = 0; db < 8; db++) {
        bf16x4 pk4 = { (__bf16)(o[db][0] * inv_l), (__bf16)(o[db][1] * inv_l),
                       (__bf16)(o[db][2] * inv_l), (__bf16)(o[db][3] * inv_l) };
        *(bf16x4*)&Out[obase + db * 16] = pk4;
    }
}

// ---------------------------------------------------------------------------
extern "C" void kernel_launch(void* const* d_in, const int* in_sizes, int n_in,
                              void* d_out, int out_size, void* d_ws, size_t ws_size,
                              hipStream_t stream) {
    const float* X  = (const float*)d_in[0];
    const float* tv = (const float*)d_in[1];
    const float* wq = (const float*)d_in[2];
    const float* bq = (const float*)d_in[3];
    const float* wk = (const float*)d_in[4];
    const float* bk = (const float*)d_in[5];
    const float* wv = (const float*)d_in[6];
    const float* bv = (const float*)d_in[7];
    const float* wo = (const float*)d_in[8];
    const float* rw = (const float*)d_in[9];

    // Workspace (~56 MB):
    //   Wt 12.6MB ([wq|wk|wv]^T -> reused for wo^T after gemm1)
    //   bsf 12KB, Tab 1MB, Qr 16.8MB, Kr/Vt 8.4MB, AO 16.8MB (=Xb alias)
    char* ws = (char*)d_ws;
    unsigned short* Wt  = (unsigned short*)ws; ws += 3072L * 2048 * 2;
    float*          bsf = (float*)ws;          ws += 3072L * 4;
    unsigned int*   Tab = (unsigned int*)ws;   ws += 4096L * 64 * 4;
    unsigned short* Qr  = (unsigned short*)ws; ws += (long)BATCH * NH  * S_LEN * HD * 2;
    unsigned short* Kr  = (unsigned short*)ws; ws += (long)BATCH * NKV * S_LEN * HD * 2;
    unsigned short* Vt  = (unsigned short*)ws; ws += (long)BATCH * NKV * HD * S_LEN * 2;
    unsigned short* AO  = (unsigned short*)ws; ws += 4096L * 2048 * 2;
    unsigned short* Xb  = AO;   // alias: Xb dead (post-gemm1) before attn writes AO

    transpose_qkv<<<dim3(64, 64, 3), dim3(32, 8), 0, stream>>>(wq, wk, wv, Wt);
    prep_kernel<<<4096, 256, 0, stream>>>(X, Xb, bq, bk, bv, bsf, tv, rw, Tab);
    gemm_qkv_rope<<<dim3(12, 16), 512, 0, stream>>>(Xb, Wt, bsf, Tab, Qr, Kr, Vt);
    transpose_to_bf16<<<dim3(64, 64), dim3(32, 8), 0, stream>>>(wo, Wt, 2048, 2048, 0L, 2048);
    attn_kernel<<<dim3(32, 16, 1), 512, 0, stream>>>(Qr, Kr, Vt, AO);
    gemm_o<<<dim3(8, 32), 512, 0, stream>>>(AO, Wt, (float*)d_out);
}

// Round 7
// 290.190 us; speedup vs baseline: 1.0629x; 1.0384x over previous
//
#include <hip/hip_runtime.h>

// ---------------------------------------------------------------------------
// TimeMoeAttention: X@Wq/Wk/Wv + bias -> continuous-time RoPE -> causal GQA
// attention -> @Wo.  B=2, S=2048, H=2048, NH=16, NKV=4, HD=128.
// I/O fp32; internal bf16 + fp32 MFMA accumulation.
// R17: launch-count consolidation (6 -> 4 kernels), math untouched.
//  - prep_all = prep_kernel + transpose_qkv fused (10240 blocks; ranges).
//  - attn_kernel grid (32,18): y>=16 -> 64 blocks transpose wo -> Wt region
//    (dead after gemm1), co-resident on the 3rd block/CU slot attn leaves
//    free; removes transpose_to_bf16 launch from the critical path.
//  - gemm_qkv_rope (R11 8-phase) and gemm_o (R16 4-phase) unchanged.
// ---------------------------------------------------------------------------

#define S_LEN 2048
#define BATCH 2
#define NH    16
#define NKV   4
#define HD    128

typedef float  f32x4  __attribute__((ext_vector_type(4)));
typedef __bf16 bf16x8 __attribute__((ext_vector_type(8)));
typedef __bf16 bf16x4 __attribute__((ext_vector_type(4)));
typedef unsigned int u32x4 __attribute__((ext_vector_type(4)));
typedef unsigned int u32x2 __attribute__((ext_vector_type(2)));

__device__ inline unsigned short f2bf(float f) {
    unsigned u = __builtin_bit_cast(unsigned, f);
    unsigned r = (u + 0x7fffu + ((u >> 16) & 1u)) >> 16;   // RNE
    return (unsigned short)r;
}

// async global->LDS, 16 bytes per lane (dest = wave-uniform base + lane*16)
__device__ inline void gload_lds16(const void* g, void* l) {
    __builtin_amdgcn_global_load_lds(
        (const __attribute__((address_space(1))) unsigned int*)g,
        (__attribute__((address_space(3))) unsigned int*)l, 16, 0, 0);
}

// ---------------------------------------------------------------------------
// prep_all: fusion of prep_kernel + transpose_qkv.
//   bi in [0,4096):    X fp32->bf16 (8 elems/thr); bi<12: bias concat;
//                      bi<1024: rope table.
//   bi in [4096,10240): wq|wk|wv fp32 -> Wt bf16 transpose, 32x32 tiles.
//      t = bi-4096: t<4096 -> z=0 (wq, 64x64 tiles); t<5120 -> z=1 (wk,
//      16x64); else z=2 (wv, 16x64).  Thread map (32,8)x4 from 256 linear.
// ---------------------------------------------------------------------------
__global__ __launch_bounds__(256) void prep_all(
        const float* __restrict__ X, unsigned short* __restrict__ Xb,
        const float* __restrict__ bq, const float* __restrict__ bk,
        const float* __restrict__ bv, float* __restrict__ bsf,
        const float* __restrict__ tv, const float* __restrict__ rw,
        unsigned int* __restrict__ Tab,
        const float* __restrict__ wq, const float* __restrict__ wk,
        const float* __restrict__ wv, unsigned short* __restrict__ Wt) {
    __shared__ unsigned short tt[32][33];
    const int bi = blockIdx.x, tid = threadIdx.x;

    if (bi < 4096) {
        long i = ((long)bi * 256 + tid) * 8;
        {
            f32x4 a = *(const f32x4*)&X[i];
            f32x4 b = *(const f32x4*)&X[i + 4];
            u32x4 r;
            r.x = (unsigned)f2bf(a[0]) | ((unsigned)f2bf(a[1]) << 16);
            r.y = (unsigned)f2bf(a[2]) | ((unsigned)f2bf(a[3]) << 16);
            r.z = (unsigned)f2bf(b[0]) | ((unsigned)f2bf(b[1]) << 16);
            r.w = (unsigned)f2bf(b[2]) | ((unsigned)f2bf(b[3]) << 16);
            *(u32x4*)&Xb[i] = r;
        }
        if (bi < 12) {
            int ib = bi * 256 + tid;
            bsf[ib] = (ib < 2048) ? bq[ib] : ((ib < 2560) ? bk[ib - 2048] : bv[ib - 2560]);
        }
        if (bi < 1024) {
            int m = bi * 4 + (tid >> 6);
            int fi = tid & 63;
            float t = tv[m];
            float f = t * powf(10000.f, -(float)fi / 64.f) * rw[fi];
            Tab[m * 64 + fi] = (unsigned)f2bf(cosf(f)) | ((unsigned)f2bf(sinf(f)) << 16);
        }
        return;
    }

    const int t = bi - 4096;
    int z, ti;
    if (t < 4096)      { z = 0; ti = t; }
    else if (t < 5120) { z = 1; ti = t - 4096; }
    else               { z = 2; ti = t - 5120; }
    const float* src = (z == 0) ? wq : ((z == 1) ? wk : wv);
    const int  C    = (z == 0) ? 2048 : 512;
    const long doff = (z == 0) ? 0L : ((z == 1) ? 2048L * 2048 : 2560L * 2048);
    const int bx = (z == 0) ? (ti & 63) * 32 : (ti & 15) * 32;
    const int by = (z == 0) ? (ti >> 6) * 32 : (ti >> 4) * 32;
    const int x = tid & 31, y0 = tid >> 5;
    #pragma unroll
    for (int i = 0; i < 4; i++) {
        int y = y0 + i * 8;
        tt[y][x] = f2bf(src[(long)(by + y) * C + bx + x]);
    }
    __syncthreads();
    #pragma unroll
    for (int i = 0; i < 4; i++) {
        int y = y0 + i * 8;
        Wt[doff + (long)(bx + y) * 2048 + by + x] = tt[x][y];
    }
}

// ---------------------------------------------------------------------------
// 256x256 8-phase GEMM machinery (R11; proven).  LDS slots: A(buf,ks) at
// buf*16384+ks*8192, B at +32768.  Slot=256rx32k, XOR-swizzled
// kgrp^((row>>1)&3).  Staging: linear LDS dest + pre-swizzled global col.
// vmcnt(6) at phases 4/8 only.
// ---------------------------------------------------------------------------
__device__ __forceinline__ void stage_half(const unsigned short* __restrict__ G,
        int baseRow, long kc, unsigned short* slot, int r0, int c0, int tid) {
    gload_lds16(&G[(long)(baseRow + r0) * 2048 + kc + c0], &slot[tid * 8]);
    gload_lds16(&G[(long)(baseRow + r0 + 128) * 2048 + kc + c0], &slot[4096 + tid * 8]);
}

#define STG_A(buf, ks, kt) \
    stage_half(A,  m0, (long)(kt) * 64 + (ks) * 32, &sm[(buf) * 16384 + (ks) * 8192], r0s, c0s, tid)
#define STG_B(buf, ks, kt) \
    stage_half(Bt, n0, (long)(kt) * 64 + (ks) * 32, &sm[32768 + (buf) * 16384 + (ks) * 8192], r0s, c0s, tid)

#define NOPV ((void)0)
#define VM6  asm volatile("s_waitcnt vmcnt(6)" ::: "memory")

#define PH(buf, ks, mh, RDB, STG, VM)                                          \
    {                                                                          \
        const int sb_ = (buf) * 16384 + (ks) * 8192;                           \
        bf16x8 a0 = *(const bf16x8*)&sm[sb_ + abase + (mh) * 2048];            \
        bf16x8 a1 = *(const bf16x8*)&sm[sb_ + abase + (mh) * 2048 + 512];      \
        bf16x8 a2 = *(const bf16x8*)&sm[sb_ + abase + (mh) * 2048 + 1024];     \
        bf16x8 a3 = *(const bf16x8*)&sm[sb_ + abase + (mh) * 2048 + 1536];     \
        if (RDB) {                                                             \
            b0 = *(const bf16x8*)&sm[sb_ + bbase];                             \
            b1 = *(const bf16x8*)&sm[sb_ + bbase + 512];                       \
            b2 = *(const bf16x8*)&sm[sb_ + bbase + 1024];                      \
            b3 = *(const bf16x8*)&sm[sb_ + bbase + 1536];                      \
        }                                                                      \
        STG;                                                                   \
        VM;                                                                    \
        __builtin_amdgcn_s_barrier();                                          \
        asm volatile("s_waitcnt lgkmcnt(0)" ::: "memory");                     \
        __builtin_amdgcn_sched_barrier(0);                                     \
        __builtin_amdgcn_s_setprio(1);                                         \
        _Pragma("unroll") for (int mi = 0; mi < 4; ++mi) {                     \
            bf16x8 am = (mi == 0) ? a0 : (mi == 1) ? a1 : (mi == 2) ? a2 : a3; \
            acc[(mh) * 4 + mi][0] = __builtin_amdgcn_mfma_f32_16x16x32_bf16(   \
                am, b0, acc[(mh) * 4 + mi][0], 0, 0, 0);                       \
            acc[(mh) * 4 + mi][1] = __builtin_amdgcn_mfma_f32_16x16x32_bf16(   \
                am, b1, acc[(mh) * 4 + mi][1], 0, 0, 0);                       \
            acc[(mh) * 4 + mi][2] = __builtin_amdgcn_mfma_f32_16x16x32_bf16(   \
                am, b2, acc[(mh) * 4 + mi][2], 0, 0, 0);                       \
            acc[(mh) * 4 + mi][3] = __builtin_amdgcn_mfma_f32_16x16x32_bf16(   \
                am, b3, acc[(mh) * 4 + mi][3], 0, 0, 0);                       \
        }                                                                      \
        __builtin_amdgcn_s_setprio(0);                                         \
        __builtin_amdgcn_s_barrier();                                          \
    }

#define GEMM_PRO_LOOP(NIT)                                                     \
    STG_B(0, 0, 0); STG_A(0, 0, 0); STG_B(0, 1, 0); STG_A(0, 1, 0);            \
    STG_B(1, 0, 1); STG_A(1, 0, 1); STG_B(1, 1, 1);                            \
    asm volatile("s_waitcnt vmcnt(6)" ::: "memory");                           \
    __builtin_amdgcn_s_barrier();                                              \
    for (int it = 0; it < (NIT); ++it) {                                       \
        const int t1  = 2 * it + 1;                                            \
        const int tn0 = (it < (NIT) - 1) ? 2 * it + 2 : 2 * (NIT) - 1;         \
        const int tn1 = (it < (NIT) - 1) ? 2 * it + 3 : 2 * (NIT) - 1;         \
        PH(0, 0, 0, 1, STG_A(1, 1, t1),  NOPV);                                \
        PH(0, 0, 1, 0, STG_B(0, 0, tn0), NOPV);                                \
        PH(0, 1, 0, 1, STG_A(0, 0, tn0), NOPV);                                \
        PH(0, 1, 1, 0, STG_B(0, 1, tn0), VM6);                                 \
        PH(1, 0, 0, 1, STG_A(0, 1, tn0), NOPV);                                \
        PH(1, 0, 1, 0, STG_B(1, 0, tn1), NOPV);                                \
        PH(1, 1, 0, 1, STG_A(1, 0, tn1), NOPV);                                \
        PH(1, 1, 1, 0, STG_B(1, 1, tn1), VM6);                                 \
    }

// ---------------------------------------------------------------------------
// GEMM1 + bias + RoPE fused, 256x256 8-phase schedule (R11).
// Grid (12,16): bx 0..7 -> Q heads 2bx,2bx+1; 8,9 -> K; 10,11 -> V.
// ---------------------------------------------------------------------------
__global__ __launch_bounds__(512, 2) void gemm_qkv_rope(
        const unsigned short* __restrict__ A,
        const unsigned short* __restrict__ Bt,
        const float* __restrict__ bsf,
        const unsigned int* __restrict__ Tab,
        unsigned short* __restrict__ Qr,
        unsigned short* __restrict__ Kr,
        unsigned short* __restrict__ Vt) {
    __shared__ __align__(16) unsigned short sm[65536];   // 128 KiB

    const int tid = threadIdx.x;
    const int wid = tid >> 6, lane = tid & 63, quad = lane >> 4, l16 = lane & 15;
    const int wr = wid >> 2, wc = wid & 3;               // 2M x 4N waves

    // XCD-aware bijective swizzle (192 blocks, 192 % 8 == 0)
    const int u   = blockIdx.y * 12 + blockIdx.x;
    const int swz = (u & 7) * 24 + (u >> 3);
    const int bx  = swz % 12;
    const int m0  = (swz / 12) * 256;
    const int n0  = bx * 256;

    // fragment-read addressing (XOR bank swizzle on the k-group)
    const int sg    = (quad ^ ((l16 >> 1) & 3)) * 8;
    const int abase = wr * 4096 + l16 * 32 + sg;
    const int bbase = 32768 + wc * 2048 + l16 * 32 + sg;

    // staging addressing: linear LDS dest, pre-swizzled global column
    const int r0s = tid >> 2;
    const int c0s = ((tid & 3) ^ ((r0s >> 1) & 3)) * 8;

    f32x4 acc[8][4];
    #pragma unroll
    for (int i = 0; i < 8; i++)
        #pragma unroll
        for (int j = 0; j < 4; j++)
            #pragma unroll
            for (int c = 0; c < 4; c++) acc[i][j][c] = 0.f;
    bf16x8 b0 = {}, b1 = {}, b2 = {}, b3 = {};

    GEMM_PRO_LOOP(16)

    // drain stray prefetches before reusing smem for the epilogue
    asm volatile("s_waitcnt vmcnt(0)" ::: "memory");
    __syncthreads();

    // ---- fused epilogue: bias + RoPE (Q,K) / transpose (V), 8x32 tokens ----
    float* Ep = (float*)sm;
    const int EPLD = 264;                                // 256 + 8 pad
    float bv4[4];
    #pragma unroll
    for (int ni = 0; ni < 4; ++ni) bv4[ni] = bsf[n0 + wc * 64 + ni * 16 + l16];
    const bool isV = (bx >= 10);
    const float qs = (bx < 8) ? (0.08838834764831845f * 1.4426950408889634f) : 1.0f;

    const int lt = tid >> 4, hh = (tid >> 3) & 1, jj = tid & 7, j0 = jj * 8;
    const int vd = tid >> 1, vsh = tid & 1;

    #pragma unroll
    for (int p = 0; p < 8; ++p) {
        if (wr == (p >> 2)) {
            #pragma unroll
            for (int f = 0; f < 2; ++f) {
                #pragma unroll
                for (int ni = 0; ni < 4; ++ni)
                    #pragma unroll
                    for (int r = 0; r < 4; ++r)
                        Ep[(f * 16 + quad * 4 + r) * EPLD + wc * 64 + ni * 16 + l16] =
                            acc[(p & 3) * 2 + f][ni][r] + bv4[ni];
            }
        }
        __syncthreads();
        if (!isV) {
            const int gm = m0 + p * 32 + lt;
            const int bb = gm >> 11, s = gm & 2047;
            unsigned short* dst = (bx < 8)
                ? Qr + ((long)(bb * NH + bx * 2 + hh) * S_LEN + s) * HD
                : Kr + ((long)(bb * NKV + (bx - 8) * 2 + hh) * S_LEN + s) * HD;
            u32x4 t0 = *(const u32x4*)&Tab[(long)gm * 64 + j0];
            u32x4 t1v = *(const u32x4*)&Tab[(long)gm * 64 + j0 + 4];
            f32x4 x1a = *(f32x4*)&Ep[lt * EPLD + hh * 128 + j0];
            f32x4 x1b = *(f32x4*)&Ep[lt * EPLD + hh * 128 + j0 + 4];
            f32x4 x2a = *(f32x4*)&Ep[lt * EPLD + hh * 128 + 64 + j0];
            f32x4 x2b = *(f32x4*)&Ep[lt * EPLD + hh * 128 + 64 + j0 + 4];
            f32x4 la, lb, ha, hb;
            #pragma unroll
            for (int e = 0; e < 4; e++) {
                float ca = __builtin_bit_cast(float, t0[e] << 16);
                float sa = __builtin_bit_cast(float, t0[e] & 0xffff0000u);
                float cb = __builtin_bit_cast(float, t1v[e] << 16);
                float sbv = __builtin_bit_cast(float, t1v[e] & 0xffff0000u);
                la[e] = (x1a[e] * ca - x2a[e] * sa) * qs;
                ha[e] = (x2a[e] * ca + x1a[e] * sa) * qs;
                lb[e] = (x1b[e] * cb - x2b[e] * sbv) * qs;
                hb[e] = (x2b[e] * cb + x1b[e] * sbv) * qs;
            }
            u32x4 lo, hi;
            lo.x = (unsigned)f2bf(la[0]) | ((unsigned)f2bf(la[1]) << 16);
            lo.y = (unsigned)f2bf(la[2]) | ((unsigned)f2bf(la[3]) << 16);
            lo.z = (unsigned)f2bf(lb[0]) | ((unsigned)f2bf(lb[1]) << 16);
            lo.w = (unsigned)f2bf(lb[2]) | ((unsigned)f2bf(lb[3]) << 16);
            hi.x = (unsigned)f2bf(ha[0]) | ((unsigned)f2bf(ha[1]) << 16);
            hi.y = (unsigned)f2bf(ha[2]) | ((unsigned)f2bf(ha[3]) << 16);
            hi.z = (unsigned)f2bf(hb[0]) | ((unsigned)f2bf(hb[1]) << 16);
            hi.w = (unsigned)f2bf(hb[2]) | ((unsigned)f2bf(hb[3]) << 16);
            *(u32x4*)&dst[j0] = lo;
            *(u32x4*)&dst[64 + j0] = hi;
        } else {
            const int gmb = m0 + p * 32 + vsh * 16;
            const int bb = gmb >> 11, s0 = gmb & 2047;
            const int vh = (bx - 10) * 2 + (vd >> 7), dl = vd & 127;
            unsigned short* dst = Vt + ((long)(bb * NKV + vh) * HD + dl) * S_LEN + s0;
            unsigned short pv[16];
            #pragma unroll
            for (int t = 0; t < 16; ++t)
                pv[t] = f2bf(Ep[(vsh * 16 + t) * EPLD + vd]);
            u32x4 v0, v1;
            v0.x = (unsigned)pv[0]  | ((unsigned)pv[1]  << 16);
            v0.y = (unsigned)pv[2]  | ((unsigned)pv[3]  << 16);
            v0.z = (unsigned)pv[4]  | ((unsigned)pv[5]  << 16);
            v0.w = (unsigned)pv[6]  | ((unsigned)pv[7]  << 16);
            v1.x = (unsigned)pv[8]  | ((unsigned)pv[9]  << 16);
            v1.y = (unsigned)pv[10] | ((unsigned)pv[11] << 16);
            v1.z = (unsigned)pv[12] | ((unsigned)pv[13] << 16);
            v1.w = (unsigned)pv[14] | ((unsigned)pv[15] << 16);
            *(u32x4*)&dst[0] = v0;
            *(u32x4*)&dst[8] = v1;
        }
        __syncthreads();
    }
}

// ---------------------------------------------------------------------------
// GEMM2 (R16): d_out fp32 = AO bf16 [4096][2048] x Wt(wo^T) [2048][2048]^T.
// 128x256 tiles -> 256 blocks (1/CU).  8 waves 2Mx4N, wave-tile 64x64,
// acc[4][4].  LDS 96KiB.  4 phases/iter, uniform vmcnt(6).
// ---------------------------------------------------------------------------
#define OSTG_A(buf, ks, kt)                                                    \
    gload_lds16(&A[(long)(m0 + r0s) * 2048 + (kt) * 64 + (ks) * 32 + c0s],     \
                &sm[((buf) * 2 + (ks)) * 4096 + tid * 8])
#define OSTG_B(buf, ks, kt)                                                    \
    stage_half(Bt, n0, (long)(kt) * 64 + (ks) * 32,                            \
               &sm[16384 + ((buf) * 2 + (ks)) * 8192], r0s, c0s, tid)

#define OPH(buf, ks, STG)                                                      \
    {                                                                          \
        const int ab_ = ((buf) * 2 + (ks)) * 4096 + abase;                     \
        const int bb_ = ((buf) * 2 + (ks)) * 8192 + bbase;                     \
        bf16x8 a0 = *(const bf16x8*)&sm[ab_];                                  \
        bf16x8 a1 = *(const bf16x8*)&sm[ab_ + 512];                            \
        bf16x8 a2 = *(const bf16x8*)&sm[ab_ + 1024];                           \
        bf16x8 a3 = *(const bf16x8*)&sm[ab_ + 1536];                           \
        bf16x8 b0 = *(const bf16x8*)&sm[bb_];                                  \
        bf16x8 b1 = *(const bf16x8*)&sm[bb_ + 512];                            \
        bf16x8 b2 = *(const bf16x8*)&sm[bb_ + 1024];                           \
        bf16x8 b3 = *(const bf16x8*)&sm[bb_ + 1536];                           \
        STG;                                                                   \
        asm volatile("s_waitcnt vmcnt(6)" ::: "memory");                       \
        __builtin_amdgcn_s_barrier();                                          \
        asm volatile("s_waitcnt lgkmcnt(0)" ::: "memory");                     \
        __builtin_amdgcn_sched_barrier(0);                                     \
        __builtin_amdgcn_s_setprio(1);                                         \
        _Pragma("unroll") for (int mi = 0; mi < 4; ++mi) {                     \
            bf16x8 am = (mi == 0) ? a0 : (mi == 1) ? a1 : (mi == 2) ? a2 : a3; \
            acc[mi][0] = __builtin_amdgcn_mfma_f32_16x16x32_bf16(              \
                am, b0, acc[mi][0], 0, 0, 0);                                  \
            acc[mi][1] = __builtin_amdgcn_mfma_f32_16x16x32_bf16(              \
                am, b1, acc[mi][1], 0, 0, 0);                                  \
            acc[mi][2] = __builtin_amdgcn_mfma_f32_16x16x32_bf16(              \
                am, b2, acc[mi][2], 0, 0, 0);                                  \
            acc[mi][3] = __builtin_amdgcn_mfma_f32_16x16x32_bf16(              \
                am, b3, acc[mi][3], 0, 0, 0);                                  \
        }                                                                      \
        __builtin_amdgcn_s_setprio(0);                                         \
        __builtin_amdgcn_s_barrier();                                          \
    }

__global__ __launch_bounds__(512, 2) void gemm_o(
        const unsigned short* __restrict__ A,
        const unsigned short* __restrict__ Bt,
        float* __restrict__ C) {
    __shared__ __align__(16) unsigned short sm[49152];   // 96 KiB

    const int tid = threadIdx.x;
    const int wid = tid >> 6, lane = tid & 63, quad = lane >> 4, l16 = lane & 15;
    const int wr = wid >> 2, wc = wid & 3;               // 2M x 4N, tile 64x64

    // XCD swizzle: grid (8,32) = 256 blocks; same-XCD blocks share n-tile
    const int u   = blockIdx.y * 8 + blockIdx.x;
    const int swz = (u & 7) * 32 + (u >> 3);
    const int m0  = (swz & 31) * 128;
    const int n0  = (swz >> 5) * 256;

    const int sg    = (quad ^ ((l16 >> 1) & 3)) * 8;
    const int abase = (wr * 64 + l16) * 32 + sg;
    const int bbase = 16384 + (wc * 64 + l16) * 32 + sg;
    const int r0s = tid >> 2;
    const int c0s = ((tid & 3) ^ ((r0s >> 1) & 3)) * 8;

    f32x4 acc[4][4];
    #pragma unroll
    for (int i = 0; i < 4; i++)
        #pragma unroll
        for (int j = 0; j < 4; j++)
            #pragma unroll
            for (int c = 0; c < 4; c++) acc[i][j][c] = 0.f;

    // prologue: tile0 full + tile1 partial (A10,B10); first batch = A00+B00
    OSTG_A(0, 0, 0); OSTG_B(0, 0, 0);
    OSTG_A(0, 1, 0); OSTG_B(0, 1, 0);
    OSTG_A(1, 0, 1); OSTG_B(1, 0, 1);
    asm volatile("s_waitcnt vmcnt(6)" ::: "memory");     // A00,B00 landed
    __builtin_amdgcn_s_barrier();

    for (int it = 0; it < 16; ++it) {
        const int t1  = 2 * it + 1;
        const int tn0 = (it < 15) ? 2 * it + 2 : 31;     // tail: reload, unread
        const int tn1 = (it < 15) ? 2 * it + 3 : 31;
        OPH(0, 0, OSTG_A(1, 1, t1);  OSTG_B(1, 1, t1))
        OPH(0, 1, OSTG_A(0, 0, tn0); OSTG_B(0, 0, tn0))
        OPH(1, 0, OSTG_A(0, 1, tn0); OSTG_B(0, 1, tn0))
        OPH(1, 1, OSTG_A(1, 0, tn1); OSTG_B(1, 0, tn1))
    }

    asm volatile("s_waitcnt vmcnt(0)" ::: "memory");     // drain tail prefetch

    #pragma unroll
    for (int mi = 0; mi < 4; mi++)
        #pragma unroll
        for (int ni = 0; ni < 4; ni++) {
            const int gn = n0 + wc * 64 + ni * 16 + l16;
            #pragma unroll
            for (int r = 0; r < 4; r++) {
                const int gm = m0 + wr * 64 + mi * 16 + quad * 4 + r;
                C[(long)gm * 2048 + gn] = acc[mi][ni][r];
            }
        }
}

// ---------------------------------------------------------------------------
// Causal flash attention, GQA, transposed scores (R13, proven) + fused wo
// transpose.  Grid (32,18): y<16 -> attn (x%8 = b*4+hk XCD remap, qt =
// y<8?y:23-y pairing, T13 defer-max); y>=16 -> 64 blocks transpose wo fp32
// -> Wt bf16 (Wt region dead after gemm1; gemm_o reads it next).  The 64
// transpose blocks occupy the 3rd block/CU slot attn leaves free.
// ---------------------------------------------------------------------------
__global__ __launch_bounds__(512, 4) void attn_kernel(
        const unsigned short* __restrict__ Qr,
        const unsigned short* __restrict__ Kr,
        const unsigned short* __restrict__ Vt,
        unsigned short* __restrict__ Out,
        const float* __restrict__ wo,
        unsigned short* __restrict__ WoT) {
    __shared__ __align__(16) unsigned short Ks[64 * 128];
    __shared__ __align__(16) unsigned short Vs[128 * 64];
    __shared__ __align__(16) unsigned short Ps[8][16 * 68];

    if (blockIdx.y >= 16) {                              // wo-transpose blocks
        unsigned short (*tt)[33] = (unsigned short (*)[33])Ks;   // alias
        const int widx = blockIdx.x + (blockIdx.y - 16) * 32;    // [0,64)
        const int x = threadIdx.x & 31, yy = threadIdx.x >> 5;   // [0,16)
        for (int j = 0; j < 64; ++j) {
            const int idx = widx * 64 + j;
            const int bx = (idx & 63) * 32, by = (idx >> 6) * 32;
            #pragma unroll
            for (int i = 0; i < 2; ++i) {
                int y = yy + i * 16;
                tt[y][x] = f2bf(wo[(long)(by + y) * 2048 + bx + x]);
            }
            __syncthreads();
            #pragma unroll
            for (int i = 0; i < 2; ++i) {
                int y = yy + i * 16;
                WoT[(long)(bx + y) * 2048 + by + x] = tt[x][y];
            }
            __syncthreads();
        }
        return;
    }

    const int x = blockIdx.x, y = blockIdx.y;
    const int hk = x & 3, b = (x >> 2) & 1;
    const int h  = ((x & 3) << 2) + (x >> 3);            // h>>2 == hk
    const int qt = (y < 8) ? y : 23 - y;                 // pairs sum to 23
    const int tid = threadIdx.x, w = tid >> 6, lane = tid & 63;
    const int quad = lane >> 4, l16 = lane & 15;
    const unsigned short* Qb = Qr + (long)((b * NH + h) * S_LEN) * HD;
    const unsigned short* Kb = Kr + (long)((b * NKV + hk) * S_LEN) * HD;
    const unsigned short* Vb = Vt + (long)((b * NKV + hk) * HD) * S_LEN;
    const int qw = qt * 128 + w * 16;
    const int q  = qw + l16;
    const float MASK_MIN = -3.0e38f;

    bf16x8 qf[4];
    #pragma unroll
    for (int kc = 0; kc < 4; kc++)
        qf[kc] = *(const bf16x8*)&Qb[(long)q * HD + kc * 32 + quad * 8];

    f32x4 o[8];
    #pragma unroll
    for (int db = 0; db < 8; db++)
        #pragma unroll
        for (int c = 0; c < 4; c++) o[db][c] = 0.f;
    float mr = MASK_MIN, lr = 0.f;

    const int sK0 = tid, sK1 = tid + 512;
    const int kR0 = sK0 >> 4, kC0 = ((sK0 & 15) ^ (kR0 & 15)) * 8;
    const int kR1 = sK1 >> 4, kC1 = ((sK1 & 15) ^ (kR1 & 15)) * 8;
    const int vR0 = sK0 >> 3, vC0 = ((sK0 & 7) ^ (vR0 & 7)) * 8;
    const int vR1 = sK1 >> 3, vC1 = ((sK1 & 7) ^ (vR1 & 7)) * 8;

    const int nkt = 2 * qt + 2;
    for (int kt = 0; kt < nkt; kt++) {
        const int k0 = kt * 64;
        __syncthreads();
        gload_lds16(&Kb[(long)(k0 + kR0) * HD + kC0], &Ks[sK0 * 8]);
        gload_lds16(&Kb[(long)(k0 + kR1) * HD + kC1], &Ks[sK1 * 8]);
        gload_lds16(&Vb[(long)vR0 * S_LEN + k0 + vC0], &Vs[sK0 * 8]);
        gload_lds16(&Vb[(long)vR1 * S_LEN + k0 + vC1], &Vs[sK1 * 8]);
        __syncthreads();

        if (k0 > qw + 15) continue;

        f32x4 sc[4];
        #pragma unroll
        for (int nb = 0; nb < 4; nb++) {
            #pragma unroll
            for (int c = 0; c < 4; c++) sc[nb][c] = 0.f;
            #pragma unroll
            for (int kc = 0; kc < 4; kc++) {
                bf16x8 kf = *(const bf16x8*)
                    &Ks[(nb * 16 + l16) * 128 + (((kc * 4 + quad) ^ l16) * 8)];
                sc[nb] = __builtin_amdgcn_mfma_f32_16x16x32_bf16(kf, qf[kc], sc[nb], 0, 0, 0);
            }
        }
        if (k0 + 63 > qw) {   // diagonal tile: mask only (Q pre-scaled)
            #pragma unroll
            for (int nb = 0; nb < 4; nb++) {
                int kvb = k0 + nb * 16 + quad * 4;
                #pragma unroll
                for (int r = 0; r < 4; r++)
                    sc[nb][r] = (kvb + r > q) ? MASK_MIN : sc[nb][r];
            }
        }
        float tm = MASK_MIN;
        #pragma unroll
        for (int nb = 0; nb < 4; nb++)
            #pragma unroll
            for (int r = 0; r < 4; r++) tm = fmaxf(tm, sc[nb][r]);
        tm = fmaxf(tm, __shfl_xor(tm, 16));
        tm = fmaxf(tm, __shfl_xor(tm, 32));

        float mn = mr;
        if (__any(tm > mr + 8.f)) {         // T13: rescale only on growth > 8
            mn = fmaxf(mr, tm);
            float alpha = exp2f(mr - mn);
            mr = mn;
            lr *= alpha;
            #pragma unroll
            for (int db = 0; db < 8; db++)
                #pragma unroll
                for (int c = 0; c < 4; c++) o[db][c] *= alpha;
        }
        float rs = 0.f;
        #pragma unroll
        for (int nb = 0; nb < 4; nb++) {
            float pv0 = exp2f(sc[nb][0] - mn), pv1 = exp2f(sc[nb][1] - mn);
            float pv2 = exp2f(sc[nb][2] - mn), pv3 = exp2f(sc[nb][3] - mn);
            rs += (pv0 + pv1) + (pv2 + pv3);
            bf16x4 pk4 = { (__bf16)pv0, (__bf16)pv1, (__bf16)pv2, (__bf16)pv3 };
            *(bf16x4*)&Ps[w][l16 * 68 + nb * 16 + quad * 4] = pk4;
        }
        rs += __shfl_xor(rs, 16);
        rs += __shfl_xor(rs, 32);
        lr += rs;

        #pragma unroll
        for (int kk = 0; kk < 2; kk++) {
            bf16x8 pf = *(const bf16x8*)&Ps[w][l16 * 68 + kk * 32 + quad * 8];
            #pragma unroll
            for (int db = 0; db < 8; db++) {
                bf16x8 vf = *(const bf16x8*)
                    &Vs[(db * 16 + l16) * 64 + (((kk * 4 + quad) ^ (l16 & 7)) * 8)];
                o[db] = __builtin_amdgcn_mfma_f32_16x16x32_bf16(vf, pf, o[db], 0, 0, 0);
            }
        }
    }

    float inv_l = 1.0f / lr;
    long obase = (long)(b * S_LEN + q) * 2048 + h * 128 + quad * 4;
    #pragma unroll
    for (int db = 0; db < 8; db++) {
        bf16x4 pk4 = { (__bf16)(o[db][0] * inv_l), (__bf16)(o[db][1] * inv_l),
                       (__bf16)(o[db][2] * inv_l), (__bf16)(o[db][3] * inv_l) };
        *(bf16x4*)&Out[obase + db * 16] = pk4;
    }
}

// ---------------------------------------------------------------------------
extern "C" void kernel_launch(void* const* d_in, const int* in_sizes, int n_in,
                              void* d_out, int out_size, void* d_ws, size_t ws_size,
                              hipStream_t stream) {
    const float* X  = (const float*)d_in[0];
    const float* tv = (const float*)d_in[1];
    const float* wq = (const float*)d_in[2];
    const float* bq = (const float*)d_in[3];
    const float* wk = (const float*)d_in[4];
    const float* bk = (const float*)d_in[5];
    const float* wv = (const float*)d_in[6];
    const float* bv = (const float*)d_in[7];
    const float* wo = (const float*)d_in[8];
    const float* rw = (const float*)d_in[9];

    // Workspace (~56 MB):
    //   Wt 12.6MB ([wq|wk|wv]^T -> reused for wo^T after gemm1)
    //   bsf 12KB, Tab 1MB, Qr 16.8MB, Kr/Vt 8.4MB, AO 16.8MB (=Xb alias)
    char* ws = (char*)d_ws;
    unsigned short* Wt  = (unsigned short*)ws; ws += 3072L * 2048 * 2;
    float*          bsf = (float*)ws;          ws += 3072L * 4;
    unsigned int*   Tab = (unsigned int*)ws;   ws += 4096L * 64 * 4;
    unsigned short* Qr  = (unsigned short*)ws; ws += (long)BATCH * NH  * S_LEN * HD * 2;
    unsigned short* Kr  = (unsigned short*)ws; ws += (long)BATCH * NKV * S_LEN * HD * 2;
    unsigned short* Vt  = (unsigned short*)ws; ws += (long)BATCH * NKV * HD * S_LEN * 2;
    unsigned short* AO  = (unsigned short*)ws; ws += 4096L * 2048 * 2;
    unsigned short* Xb  = AO;   // alias: Xb dead (post-gemm1) before attn writes AO

    prep_all<<<10240, 256, 0, stream>>>(X, Xb, bq, bk, bv, bsf, tv, rw, Tab,
                                        wq, wk, wv, Wt);
    gemm_qkv_rope<<<dim3(12, 16), 512, 0, stream>>>(Xb, Wt, bsf, Tab, Qr, Kr, Vt);
    attn_kernel<<<dim3(32, 18, 1), 512, 0, stream>>>(Qr, Kr, Vt, AO, wo, Wt);
    gemm_o<<<dim3(8, 32), 512, 0, stream>>>(AO, Wt, (float*)d_out);
}

// Round 8
// 282.764 us; speedup vs baseline: 1.0908x; 1.0263x over previous
//
#include <hip/hip_runtime.h>

// ---------------------------------------------------------------------------
// TimeMoeAttention: X@Wq/Wk/Wv + bias -> continuous-time RoPE -> causal GQA
// attention -> @Wo.  B=2, S=2048, H=2048, NH=16, NKV=4, HD=128.
// I/O fp32; internal bf16 + fp32 MFMA accumulation.
// R18: wo-transpose relocated from attn (where it cost +7.4us of contention,
//      R17 counters) into gemm1's idle CUs: gemm_qkv_rope grid 192 -> 256
//      blocks; u>=192 -> 64 transpose blocks (R17's proven loop) writing a
//      NEW WoT workspace region (Wt is read by gemm1 throughout, so wo^T
//      gets its own 8.4MB; total ws ~64MB).  attn reverts to pure R13 form
//      (proven 74.8us).  gemm_o reads WoT.  prep_all / math untouched.
// ---------------------------------------------------------------------------

#define S_LEN 2048
#define BATCH 2
#define NH    16
#define NKV   4
#define HD    128

typedef float  f32x4  __attribute__((ext_vector_type(4)));
typedef __bf16 bf16x8 __attribute__((ext_vector_type(8)));
typedef __bf16 bf16x4 __attribute__((ext_vector_type(4)));
typedef unsigned int u32x4 __attribute__((ext_vector_type(4)));
typedef unsigned int u32x2 __attribute__((ext_vector_type(2)));

__device__ inline unsigned short f2bf(float f) {
    unsigned u = __builtin_bit_cast(unsigned, f);
    unsigned r = (u + 0x7fffu + ((u >> 16) & 1u)) >> 16;   // RNE
    return (unsigned short)r;
}

// async global->LDS, 16 bytes per lane (dest = wave-uniform base + lane*16)
__device__ inline void gload_lds16(const void* g, void* l) {
    __builtin_amdgcn_global_load_lds(
        (const __attribute__((address_space(1))) unsigned int*)g,
        (__attribute__((address_space(3))) unsigned int*)l, 16, 0, 0);
}

// ---------------------------------------------------------------------------
// prep_all: fusion of prep_kernel + transpose_qkv (R17, proven).
//   bi in [0,4096):    X fp32->bf16 (8 elems/thr); bi<12: bias concat;
//                      bi<1024: rope table.
//   bi in [4096,10240): wq|wk|wv fp32 -> Wt bf16 transpose, 32x32 tiles.
// ---------------------------------------------------------------------------
__global__ __launch_bounds__(256) void prep_all(
        const float* __restrict__ X, unsigned short* __restrict__ Xb,
        const float* __restrict__ bq, const float* __restrict__ bk,
        const float* __restrict__ bv, float* __restrict__ bsf,
        const float* __restrict__ tv, const float* __restrict__ rw,
        unsigned int* __restrict__ Tab,
        const float* __restrict__ wq, const float* __restrict__ wk,
        const float* __restrict__ wv, unsigned short* __restrict__ Wt) {
    __shared__ unsigned short tt[32][33];
    const int bi = blockIdx.x, tid = threadIdx.x;

    if (bi < 4096) {
        long i = ((long)bi * 256 + tid) * 8;
        {
            f32x4 a = *(const f32x4*)&X[i];
            f32x4 b = *(const f32x4*)&X[i + 4];
            u32x4 r;
            r.x = (unsigned)f2bf(a[0]) | ((unsigned)f2bf(a[1]) << 16);
            r.y = (unsigned)f2bf(a[2]) | ((unsigned)f2bf(a[3]) << 16);
            r.z = (unsigned)f2bf(b[0]) | ((unsigned)f2bf(b[1]) << 16);
            r.w = (unsigned)f2bf(b[2]) | ((unsigned)f2bf(b[3]) << 16);
            *(u32x4*)&Xb[i] = r;
        }
        if (bi < 12) {
            int ib = bi * 256 + tid;
            bsf[ib] = (ib < 2048) ? bq[ib] : ((ib < 2560) ? bk[ib - 2048] : bv[ib - 2560]);
        }
        if (bi < 1024) {
            int m = bi * 4 + (tid >> 6);
            int fi = tid & 63;
            float t = tv[m];
            float f = t * powf(10000.f, -(float)fi / 64.f) * rw[fi];
            Tab[m * 64 + fi] = (unsigned)f2bf(cosf(f)) | ((unsigned)f2bf(sinf(f)) << 16);
        }
        return;
    }

    const int t = bi - 4096;
    int z, ti;
    if (t < 4096)      { z = 0; ti = t; }
    else if (t < 5120) { z = 1; ti = t - 4096; }
    else               { z = 2; ti = t - 5120; }
    const float* src = (z == 0) ? wq : ((z == 1) ? wk : wv);
    const int  C    = (z == 0) ? 2048 : 512;
    const long doff = (z == 0) ? 0L : ((z == 1) ? 2048L * 2048 : 2560L * 2048);
    const int bx = (z == 0) ? (ti & 63) * 32 : (ti & 15) * 32;
    const int by = (z == 0) ? (ti >> 6) * 32 : (ti >> 4) * 32;
    const int x = tid & 31, y0 = tid >> 5;
    #pragma unroll
    for (int i = 0; i < 4; i++) {
        int y = y0 + i * 8;
        tt[y][x] = f2bf(src[(long)(by + y) * C + bx + x]);
    }
    __syncthreads();
    #pragma unroll
    for (int i = 0; i < 4; i++) {
        int y = y0 + i * 8;
        Wt[doff + (long)(bx + y) * 2048 + by + x] = tt[x][y];
    }
}

// ---------------------------------------------------------------------------
// 256x256 8-phase GEMM machinery (R11; proven).  LDS slots: A(buf,ks) at
// buf*16384+ks*8192, B at +32768.  Slot=256rx32k, XOR-swizzled
// kgrp^((row>>1)&3).  Staging: linear LDS dest + pre-swizzled global col.
// vmcnt(6) at phases 4/8 only.
// ---------------------------------------------------------------------------
__device__ __forceinline__ void stage_half(const unsigned short* __restrict__ G,
        int baseRow, long kc, unsigned short* slot, int r0, int c0, int tid) {
    gload_lds16(&G[(long)(baseRow + r0) * 2048 + kc + c0], &slot[tid * 8]);
    gload_lds16(&G[(long)(baseRow + r0 + 128) * 2048 + kc + c0], &slot[4096 + tid * 8]);
}

#define STG_A(buf, ks, kt) \
    stage_half(A,  m0, (long)(kt) * 64 + (ks) * 32, &sm[(buf) * 16384 + (ks) * 8192], r0s, c0s, tid)
#define STG_B(buf, ks, kt) \
    stage_half(Bt, n0, (long)(kt) * 64 + (ks) * 32, &sm[32768 + (buf) * 16384 + (ks) * 8192], r0s, c0s, tid)

#define NOPV ((void)0)
#define VM6  asm volatile("s_waitcnt vmcnt(6)" ::: "memory")

#define PH(buf, ks, mh, RDB, STG, VM)                                          \
    {                                                                          \
        const int sb_ = (buf) * 16384 + (ks) * 8192;                           \
        bf16x8 a0 = *(const bf16x8*)&sm[sb_ + abase + (mh) * 2048];            \
        bf16x8 a1 = *(const bf16x8*)&sm[sb_ + abase + (mh) * 2048 + 512];      \
        bf16x8 a2 = *(const bf16x8*)&sm[sb_ + abase + (mh) * 2048 + 1024];     \
        bf16x8 a3 = *(const bf16x8*)&sm[sb_ + abase + (mh) * 2048 + 1536];     \
        if (RDB) {                                                             \
            b0 = *(const bf16x8*)&sm[sb_ + bbase];                             \
            b1 = *(const bf16x8*)&sm[sb_ + bbase + 512];                       \
            b2 = *(const bf16x8*)&sm[sb_ + bbase + 1024];                      \
            b3 = *(const bf16x8*)&sm[sb_ + bbase + 1536];                      \
        }                                                                      \
        STG;                                                                   \
        VM;                                                                    \
        __builtin_amdgcn_s_barrier();                                          \
        asm volatile("s_waitcnt lgkmcnt(0)" ::: "memory");                     \
        __builtin_amdgcn_sched_barrier(0);                                     \
        __builtin_amdgcn_s_setprio(1);                                         \
        _Pragma("unroll") for (int mi = 0; mi < 4; ++mi) {                     \
            bf16x8 am = (mi == 0) ? a0 : (mi == 1) ? a1 : (mi == 2) ? a2 : a3; \
            acc[(mh) * 4 + mi][0] = __builtin_amdgcn_mfma_f32_16x16x32_bf16(   \
                am, b0, acc[(mh) * 4 + mi][0], 0, 0, 0);                       \
            acc[(mh) * 4 + mi][1] = __builtin_amdgcn_mfma_f32_16x16x32_bf16(   \
                am, b1, acc[(mh) * 4 + mi][1], 0, 0, 0);                       \
            acc[(mh) * 4 + mi][2] = __builtin_amdgcn_mfma_f32_16x16x32_bf16(   \
                am, b2, acc[(mh) * 4 + mi][2], 0, 0, 0);                       \
            acc[(mh) * 4 + mi][3] = __builtin_amdgcn_mfma_f32_16x16x32_bf16(   \
                am, b3, acc[(mh) * 4 + mi][3], 0, 0, 0);                       \
        }                                                                      \
        __builtin_amdgcn_s_setprio(0);                                         \
        __builtin_amdgcn_s_barrier();                                          \
    }

#define GEMM_PRO_LOOP(NIT)                                                     \
    STG_B(0, 0, 0); STG_A(0, 0, 0); STG_B(0, 1, 0); STG_A(0, 1, 0);            \
    STG_B(1, 0, 1); STG_A(1, 0, 1); STG_B(1, 1, 1);                            \
    asm volatile("s_waitcnt vmcnt(6)" ::: "memory");                           \
    __builtin_amdgcn_s_barrier();                                              \
    for (int it = 0; it < (NIT); ++it) {                                       \
        const int t1  = 2 * it + 1;                                            \
        const int tn0 = (it < (NIT) - 1) ? 2 * it + 2 : 2 * (NIT) - 1;         \
        const int tn1 = (it < (NIT) - 1) ? 2 * it + 3 : 2 * (NIT) - 1;         \
        PH(0, 0, 0, 1, STG_A(1, 1, t1),  NOPV);                                \
        PH(0, 0, 1, 0, STG_B(0, 0, tn0), NOPV);                                \
        PH(0, 1, 0, 1, STG_A(0, 0, tn0), NOPV);                                \
        PH(0, 1, 1, 0, STG_B(0, 1, tn0), VM6);                                 \
        PH(1, 0, 0, 1, STG_A(0, 1, tn0), NOPV);                                \
        PH(1, 0, 1, 0, STG_B(1, 0, tn1), NOPV);                                \
        PH(1, 1, 0, 1, STG_A(1, 0, tn1), NOPV);                                \
        PH(1, 1, 1, 0, STG_B(1, 1, tn1), VM6);                                 \
    }

// ---------------------------------------------------------------------------
// GEMM1 + bias + RoPE fused, 256x256 8-phase schedule (R11) + wo-transpose
// on the idle CUs.  Grid (16,16) = 256 blocks: u<192 -> gemm (1 block/CU on
// 192 CUs; bx 0..7 Q, 8,9 K, 10,11 V); u>=192 -> 64 blocks transpose wo
// fp32 -> WoT bf16 (separate buffer; Wt is being read by the gemm blocks).
// ---------------------------------------------------------------------------
__global__ __launch_bounds__(512, 2) void gemm_qkv_rope(
        const unsigned short* __restrict__ A,
        const unsigned short* __restrict__ Bt,
        const float* __restrict__ bsf,
        const unsigned int* __restrict__ Tab,
        unsigned short* __restrict__ Qr,
        unsigned short* __restrict__ Kr,
        unsigned short* __restrict__ Vt,
        const float* __restrict__ wo,
        unsigned short* __restrict__ WoT) {
    __shared__ __align__(16) unsigned short sm[65536];   // 128 KiB

    const int tid = threadIdx.x;
    const int u = blockIdx.y * 16 + blockIdx.x;

    if (u >= 192) {                                      // wo-transpose blocks
        unsigned short (*tt)[33] = (unsigned short (*)[33])sm;   // alias
        const int widx = u - 192;                                // [0,64)
        const int xx = tid & 31, yy = tid >> 5;                  // [0,16)
        for (int j = 0; j < 64; ++j) {
            const int idx = widx * 64 + j;
            const int bx = (idx & 63) * 32, by = (idx >> 6) * 32;
            #pragma unroll
            for (int i = 0; i < 2; ++i) {
                int y = yy + i * 16;
                tt[y][xx] = f2bf(wo[(long)(by + y) * 2048 + bx + xx]);
            }
            __syncthreads();
            #pragma unroll
            for (int i = 0; i < 2; ++i) {
                int y = yy + i * 16;
                WoT[(long)(bx + y) * 2048 + by + xx] = tt[xx][y];
            }
            __syncthreads();
        }
        return;
    }

    const int wid = tid >> 6, lane = tid & 63, quad = lane >> 4, l16 = lane & 15;
    const int wr = wid >> 2, wc = wid & 3;               // 2M x 4N waves

    // XCD-aware bijective swizzle over the 192 gemm blocks
    const int swz = (u & 7) * 24 + (u >> 3);
    const int bx  = swz % 12;
    const int m0  = (swz / 12) * 256;
    const int n0  = bx * 256;

    // fragment-read addressing (XOR bank swizzle on the k-group)
    const int sg    = (quad ^ ((l16 >> 1) & 3)) * 8;
    const int abase = wr * 4096 + l16 * 32 + sg;
    const int bbase = 32768 + wc * 2048 + l16 * 32 + sg;

    // staging addressing: linear LDS dest, pre-swizzled global column
    const int r0s = tid >> 2;
    const int c0s = ((tid & 3) ^ ((r0s >> 1) & 3)) * 8;

    f32x4 acc[8][4];
    #pragma unroll
    for (int i = 0; i < 8; i++)
        #pragma unroll
        for (int j = 0; j < 4; j++)
            #pragma unroll
            for (int c = 0; c < 4; c++) acc[i][j][c] = 0.f;
    bf16x8 b0 = {}, b1 = {}, b2 = {}, b3 = {};

    GEMM_PRO_LOOP(16)

    // drain stray prefetches before reusing smem for the epilogue
    asm volatile("s_waitcnt vmcnt(0)" ::: "memory");
    __syncthreads();

    // ---- fused epilogue: bias + RoPE (Q,K) / transpose (V), 8x32 tokens ----
    float* Ep = (float*)sm;
    const int EPLD = 264;                                // 256 + 8 pad
    float bv4[4];
    #pragma unroll
    for (int ni = 0; ni < 4; ++ni) bv4[ni] = bsf[n0 + wc * 64 + ni * 16 + l16];
    const bool isV = (bx >= 10);
    const float qs = (bx < 8) ? (0.08838834764831845f * 1.4426950408889634f) : 1.0f;

    const int lt = tid >> 4, hh = (tid >> 3) & 1, jj = tid & 7, j0 = jj * 8;
    const int vd = tid >> 1, vsh = tid & 1;

    #pragma unroll
    for (int p = 0; p < 8; ++p) {
        if (wr == (p >> 2)) {
            #pragma unroll
            for (int f = 0; f < 2; ++f) {
                #pragma unroll
                for (int ni = 0; ni < 4; ++ni)
                    #pragma unroll
                    for (int r = 0; r < 4; ++r)
                        Ep[(f * 16 + quad * 4 + r) * EPLD + wc * 64 + ni * 16 + l16] =
                            acc[(p & 3) * 2 + f][ni][r] + bv4[ni];
            }
        }
        __syncthreads();
        if (!isV) {
            const int gm = m0 + p * 32 + lt;
            const int bb = gm >> 11, s = gm & 2047;
            unsigned short* dst = (bx < 8)
                ? Qr + ((long)(bb * NH + bx * 2 + hh) * S_LEN + s) * HD
                : Kr + ((long)(bb * NKV + (bx - 8) * 2 + hh) * S_LEN + s) * HD;
            u32x4 t0 = *(const u32x4*)&Tab[(long)gm * 64 + j0];
            u32x4 t1v = *(const u32x4*)&Tab[(long)gm * 64 + j0 + 4];
            f32x4 x1a = *(f32x4*)&Ep[lt * EPLD + hh * 128 + j0];
            f32x4 x1b = *(f32x4*)&Ep[lt * EPLD + hh * 128 + j0 + 4];
            f32x4 x2a = *(f32x4*)&Ep[lt * EPLD + hh * 128 + 64 + j0];
            f32x4 x2b = *(f32x4*)&Ep[lt * EPLD + hh * 128 + 64 + j0 + 4];
            f32x4 la, lb, ha, hb;
            #pragma unroll
            for (int e = 0; e < 4; e++) {
                float ca = __builtin_bit_cast(float, t0[e] << 16);
                float sa = __builtin_bit_cast(float, t0[e] & 0xffff0000u);
                float cb = __builtin_bit_cast(float, t1v[e] << 16);
                float sbv = __builtin_bit_cast(float, t1v[e] & 0xffff0000u);
                la[e] = (x1a[e] * ca - x2a[e] * sa) * qs;
                ha[e] = (x2a[e] * ca + x1a[e] * sa) * qs;
                lb[e] = (x1b[e] * cb - x2b[e] * sbv) * qs;
                hb[e] = (x2b[e] * cb + x1b[e] * sbv) * qs;
            }
            u32x4 lo, hi;
            lo.x = (unsigned)f2bf(la[0]) | ((unsigned)f2bf(la[1]) << 16);
            lo.y = (unsigned)f2bf(la[2]) | ((unsigned)f2bf(la[3]) << 16);
            lo.z = (unsigned)f2bf(lb[0]) | ((unsigned)f2bf(lb[1]) << 16);
            lo.w = (unsigned)f2bf(lb[2]) | ((unsigned)f2bf(lb[3]) << 16);
            hi.x = (unsigned)f2bf(ha[0]) | ((unsigned)f2bf(ha[1]) << 16);
            hi.y = (unsigned)f2bf(ha[2]) | ((unsigned)f2bf(ha[3]) << 16);
            hi.z = (unsigned)f2bf(hb[0]) | ((unsigned)f2bf(hb[1]) << 16);
            hi.w = (unsigned)f2bf(hb[2]) | ((unsigned)f2bf(hb[3]) << 16);
            *(u32x4*)&dst[j0] = lo;
            *(u32x4*)&dst[64 + j0] = hi;
        } else {
            const int gmb = m0 + p * 32 + vsh * 16;
            const int bb = gmb >> 11, s0 = gmb & 2047;
            const int vh = (bx - 10) * 2 + (vd >> 7), dl = vd & 127;
            unsigned short* dst = Vt + ((long)(bb * NKV + vh) * HD + dl) * S_LEN + s0;
            unsigned short pv[16];
            #pragma unroll
            for (int t = 0; t < 16; ++t)
                pv[t] = f2bf(Ep[(vsh * 16 + t) * EPLD + vd]);
            u32x4 v0, v1;
            v0.x = (unsigned)pv[0]  | ((unsigned)pv[1]  << 16);
            v0.y = (unsigned)pv[2]  | ((unsigned)pv[3]  << 16);
            v0.z = (unsigned)pv[4]  | ((unsigned)pv[5]  << 16);
            v0.w = (unsigned)pv[6]  | ((unsigned)pv[7]  << 16);
            v1.x = (unsigned)pv[8]  | ((unsigned)pv[9]  << 16);
            v1.y = (unsigned)pv[10] | ((unsigned)pv[11] << 16);
            v1.z = (unsigned)pv[12] | ((unsigned)pv[13] << 16);
            v1.w = (unsigned)pv[14] | ((unsigned)pv[15] << 16);
            *(u32x4*)&dst[0] = v0;
            *(u32x4*)&dst[8] = v1;
        }
        __syncthreads();
    }
}

// ---------------------------------------------------------------------------
// GEMM2 (R16): d_out fp32 = AO bf16 [4096][2048] x WoT [2048][2048]^T.
// 128x256 tiles -> 256 blocks (1/CU).  8 waves 2Mx4N, wave-tile 64x64,
// acc[4][4].  LDS 96KiB.  4 phases/iter, uniform vmcnt(6).
// ---------------------------------------------------------------------------
#define OSTG_A(buf, ks, kt)                                                    \
    gload_lds16(&A[(long)(m0 + r0s) * 2048 + (kt) * 64 + (ks) * 32 + c0s],     \
                &sm[((buf) * 2 + (ks)) * 4096 + tid * 8])
#define OSTG_B(buf, ks, kt)                                                    \
    stage_half(Bt, n0, (long)(kt) * 64 + (ks) * 32,                            \
               &sm[16384 + ((buf) * 2 + (ks)) * 8192], r0s, c0s, tid)

#define OPH(buf, ks, STG)                                                      \
    {                                                                          \
        const int ab_ = ((buf) * 2 + (ks)) * 4096 + abase;                     \
        const int bb_ = ((buf) * 2 + (ks)) * 8192 + bbase;                     \
        bf16x8 a0 = *(const bf16x8*)&sm[ab_];                                  \
        bf16x8 a1 = *(const bf16x8*)&sm[ab_ + 512];                            \
        bf16x8 a2 = *(const bf16x8*)&sm[ab_ + 1024];                           \
        bf16x8 a3 = *(const bf16x8*)&sm[ab_ + 1536];                           \
        bf16x8 b0 = *(const bf16x8*)&sm[bb_];                                  \
        bf16x8 b1 = *(const bf16x8*)&sm[bb_ + 512];                            \
        bf16x8 b2 = *(const bf16x8*)&sm[bb_ + 1024];                           \
        bf16x8 b3 = *(const bf16x8*)&sm[bb_ + 1536];                           \
        STG;                                                                   \
        asm volatile("s_waitcnt vmcnt(6)" ::: "memory");                       \
        __builtin_amdgcn_s_barrier();                                          \
        asm volatile("s_waitcnt lgkmcnt(0)" ::: "memory");                     \
        __builtin_amdgcn_sched_barrier(0);                                     \
        __builtin_amdgcn_s_setprio(1);                                         \
        _Pragma("unroll") for (int mi = 0; mi < 4; ++mi) {                     \
            bf16x8 am = (mi == 0) ? a0 : (mi == 1) ? a1 : (mi == 2) ? a2 : a3; \
            acc[mi][0] = __builtin_amdgcn_mfma_f32_16x16x32_bf16(              \
                am, b0, acc[mi][0], 0, 0, 0);                                  \
            acc[mi][1] = __builtin_amdgcn_mfma_f32_16x16x32_bf16(              \
                am, b1, acc[mi][1], 0, 0, 0);                                  \
            acc[mi][2] = __builtin_amdgcn_mfma_f32_16x16x32_bf16(              \
                am, b2, acc[mi][2], 0, 0, 0);                                  \
            acc[mi][3] = __builtin_amdgcn_mfma_f32_16x16x32_bf16(              \
                am, b3, acc[mi][3], 0, 0, 0);                                  \
        }                                                                      \
        __builtin_amdgcn_s_setprio(0);                                         \
        __builtin_amdgcn_s_barrier();                                          \
    }

__global__ __launch_bounds__(512, 2) void gemm_o(
        const unsigned short* __restrict__ A,
        const unsigned short* __restrict__ Bt,
        float* __restrict__ C) {
    __shared__ __align__(16) unsigned short sm[49152];   // 96 KiB

    const int tid = threadIdx.x;
    const int wid = tid >> 6, lane = tid & 63, quad = lane >> 4, l16 = lane & 15;
    const int wr = wid >> 2, wc = wid & 3;               // 2M x 4N, tile 64x64

    // XCD swizzle: grid (8,32) = 256 blocks; same-XCD blocks share n-tile
    const int u   = blockIdx.y * 8 + blockIdx.x;
    const int swz = (u & 7) * 32 + (u >> 3);
    const int m0  = (swz & 31) * 128;
    const int n0  = (swz >> 5) * 256;

    const int sg    = (quad ^ ((l16 >> 1) & 3)) * 8;
    const int abase = (wr * 64 + l16) * 32 + sg;
    const int bbase = 16384 + (wc * 64 + l16) * 32 + sg;
    const int r0s = tid >> 2;
    const int c0s = ((tid & 3) ^ ((r0s >> 1) & 3)) * 8;

    f32x4 acc[4][4];
    #pragma unroll
    for (int i = 0; i < 4; i++)
        #pragma unroll
        for (int j = 0; j < 4; j++)
            #pragma unroll
            for (int c = 0; c < 4; c++) acc[i][j][c] = 0.f;

    // prologue: tile0 full + tile1 partial (A10,B10); first batch = A00+B00
    OSTG_A(0, 0, 0); OSTG_B(0, 0, 0);
    OSTG_A(0, 1, 0); OSTG_B(0, 1, 0);
    OSTG_A(1, 0, 1); OSTG_B(1, 0, 1);
    asm volatile("s_waitcnt vmcnt(6)" ::: "memory");     // A00,B00 landed
    __builtin_amdgcn_s_barrier();

    for (int it = 0; it < 16; ++it) {
        const int t1  = 2 * it + 1;
        const int tn0 = (it < 15) ? 2 * it + 2 : 31;     // tail: reload, unread
        const int tn1 = (it < 15) ? 2 * it + 3 : 31;
        OPH(0, 0, OSTG_A(1, 1, t1);  OSTG_B(1, 1, t1))
        OPH(0, 1, OSTG_A(0, 0, tn0); OSTG_B(0, 0, tn0))
        OPH(1, 0, OSTG_A(0, 1, tn0); OSTG_B(0, 1, tn0))
        OPH(1, 1, OSTG_A(1, 0, tn1); OSTG_B(1, 0, tn1))
    }

    asm volatile("s_waitcnt vmcnt(0)" ::: "memory");     // drain tail prefetch

    #pragma unroll
    for (int mi = 0; mi < 4; mi++)
        #pragma unroll
        for (int ni = 0; ni < 4; ni++) {
            const int gn = n0 + wc * 64 + ni * 16 + l16;
            #pragma unroll
            for (int r = 0; r < 4; r++) {
                const int gm = m0 + wr * 64 + mi * 16 + quad * 4 + r;
                C[(long)gm * 2048 + gn] = acc[mi][ni][r];
            }
        }
}

// ---------------------------------------------------------------------------
// Causal flash attention, GQA, transposed scores (R13, proven 74.8us pure).
// Grid (32,16): x%8 = b*4+hk -> 64 blocks sharing one 2MB KV stream land on
// one XCD's L2.  qt = y<8?y:23-y balances intra-XCD pairs (sum 23).
// T13 defer-max: skip O-rescale while tile max grows <= 8 (log2 domain).
// ---------------------------------------------------------------------------
__global__ __launch_bounds__(512, 4) void attn_kernel(
        const unsigned short* __restrict__ Qr,
        const unsigned short* __restrict__ Kr,
        const unsigned short* __restrict__ Vt,
        unsigned short* __restrict__ Out) {
    __shared__ __align__(16) unsigned short Ks[64 * 128];
    __shared__ __align__(16) unsigned short Vs[128 * 64];
    __shared__ __align__(16) unsigned short Ps[8][16 * 68];

    const int x = blockIdx.x, y = blockIdx.y;
    const int hk = x & 3, b = (x >> 2) & 1;
    const int h  = ((x & 3) << 2) + (x >> 3);            // h>>2 == hk
    const int qt = (y < 8) ? y : 23 - y;                 // pairs sum to 23
    const int tid = threadIdx.x, w = tid >> 6, lane = tid & 63;
    const int quad = lane >> 4, l16 = lane & 15;
    const unsigned short* Qb = Qr + (long)((b * NH + h) * S_LEN) * HD;
    const unsigned short* Kb = Kr + (long)((b * NKV + hk) * S_LEN) * HD;
    const unsigned short* Vb = Vt + (long)((b * NKV + hk) * HD) * S_LEN;
    const int qw = qt * 128 + w * 16;
    const int q  = qw + l16;
    const float MASK_MIN = -3.0e38f;

    bf16x8 qf[4];
    #pragma unroll
    for (int kc = 0; kc < 4; kc++)
        qf[kc] = *(const bf16x8*)&Qb[(long)q * HD + kc * 32 + quad * 8];

    f32x4 o[8];
    #pragma unroll
    for (int db = 0; db < 8; db++)
        #pragma unroll
        for (int c = 0; c < 4; c++) o[db][c] = 0.f;
    float mr = MASK_MIN, lr = 0.f;

    const int sK0 = tid, sK1 = tid + 512;
    const int kR0 = sK0 >> 4, kC0 = ((sK0 & 15) ^ (kR0 & 15)) * 8;
    const int kR1 = sK1 >> 4, kC1 = ((sK1 & 15) ^ (kR1 & 15)) * 8;
    const int vR0 = sK0 >> 3, vC0 = ((sK0 & 7) ^ (vR0 & 7)) * 8;
    const int vR1 = sK1 >> 3, vC1 = ((sK1 & 7) ^ (vR1 & 7)) * 8;

    const int nkt = 2 * qt + 2;
    for (int kt = 0; kt < nkt; kt++) {
        const int k0 = kt * 64;
        __syncthreads();
        gload_lds16(&Kb[(long)(k0 + kR0) * HD + kC0], &Ks[sK0 * 8]);
        gload_lds16(&Kb[(long)(k0 + kR1) * HD + kC1], &Ks[sK1 * 8]);
        gload_lds16(&Vb[(long)vR0 * S_LEN + k0 + vC0], &Vs[sK0 * 8]);
        gload_lds16(&Vb[(long)vR1 * S_LEN + k0 + vC1], &Vs[sK1 * 8]);
        __syncthreads();

        if (k0 > qw + 15) continue;

        f32x4 sc[4];
        #pragma unroll
        for (int nb = 0; nb < 4; nb++) {
            #pragma unroll
            for (int c = 0; c < 4; c++) sc[nb][c] = 0.f;
            #pragma unroll
            for (int kc = 0; kc < 4; kc++) {
                bf16x8 kf = *(const bf16x8*)
                    &Ks[(nb * 16 + l16) * 128 + (((kc * 4 + quad) ^ l16) * 8)];
                sc[nb] = __builtin_amdgcn_mfma_f32_16x16x32_bf16(kf, qf[kc], sc[nb], 0, 0, 0);
            }
        }
        if (k0 + 63 > qw) {   // diagonal tile: mask only (Q pre-scaled)
            #pragma unroll
            for (int nb = 0; nb < 4; nb++) {
                int kvb = k0 + nb * 16 + quad * 4;
                #pragma unroll
                for (int r = 0; r < 4; r++)
                    sc[nb][r] = (kvb + r > q) ? MASK_MIN : sc[nb][r];
            }
        }
        float tm = MASK_MIN;
        #pragma unroll
        for (int nb = 0; nb < 4; nb++)
            #pragma unroll
            for (int r = 0; r < 4; r++) tm = fmaxf(tm, sc[nb][r]);
        tm = fmaxf(tm, __shfl_xor(tm, 16));
        tm = fmaxf(tm, __shfl_xor(tm, 32));

        float mn = mr;
        if (__any(tm > mr + 8.f)) {         // T13: rescale only on growth > 8
            mn = fmaxf(mr, tm);
            float alpha = exp2f(mr - mn);
            mr = mn;
            lr *= alpha;
            #pragma unroll
            for (int db = 0; db < 8; db++)
                #pragma unroll
                for (int c = 0; c < 4; c++) o[db][c] *= alpha;
        }
        float rs = 0.f;
        #pragma unroll
        for (int nb = 0; nb < 4; nb++) {
            float pv0 = exp2f(sc[nb][0] - mn), pv1 = exp2f(sc[nb][1] - mn);
            float pv2 = exp2f(sc[nb][2] - mn), pv3 = exp2f(sc[nb][3] - mn);
            rs += (pv0 + pv1) + (pv2 + pv3);
            bf16x4 pk4 = { (__bf16)pv0, (__bf16)pv1, (__bf16)pv2, (__bf16)pv3 };
            *(bf16x4*)&Ps[w][l16 * 68 + nb * 16 + quad * 4] = pk4;
        }
        rs += __shfl_xor(rs, 16);
        rs += __shfl_xor(rs, 32);
        lr += rs;

        #pragma unroll
        for (int kk = 0; kk < 2; kk++) {
            bf16x8 pf = *(const bf16x8*)&Ps[w][l16 * 68 + kk * 32 + quad * 8];
            #pragma unroll
            for (int db = 0; db < 8; db++) {
                bf16x8 vf = *(const bf16x8*)
                    &Vs[(db * 16 + l16) * 64 + (((kk * 4 + quad) ^ (l16 & 7)) * 8)];
                o[db] = __builtin_amdgcn_mfma_f32_16x16x32_bf16(vf, pf, o[db], 0, 0, 0);
            }
        }
    }

    float inv_l = 1.0f / lr;
    long obase = (long)(b * S_LEN + q) * 2048 + h * 128 + quad * 4;
    #pragma unroll
    for (int db = 0; db < 8; db++) {
        bf16x4 pk4 = { (__bf16)(o[db][0] * inv_l), (__bf16)(o[db][1] * inv_l),
                       (__bf16)(o[db][2] * inv_l), (__bf16)(o[db][3] * inv_l) };
        *(bf16x4*)&Out[obase + db * 16] = pk4;
    }
}

// ---------------------------------------------------------------------------
extern "C" void kernel_launch(void* const* d_in, const int* in_sizes, int n_in,
                              void* d_out, int out_size, void* d_ws, size_t ws_size,
                              hipStream_t stream) {
    const float* X  = (const float*)d_in[0];
    const float* tv = (const float*)d_in[1];
    const float* wq = (const float*)d_in[2];
    const float* bq = (const float*)d_in[3];
    const float* wk = (const float*)d_in[4];
    const float* bk = (const float*)d_in[5];
    const float* wv = (const float*)d_in[6];
    const float* bv = (const float*)d_in[7];
    const float* wo = (const float*)d_in[8];
    const float* rw = (const float*)d_in[9];

    // Workspace (~64 MB):
    //   Wt 12.6MB ([wq|wk|wv]^T), bsf 12KB, Tab 1MB, Qr 16.8MB, Kr/Vt 8.4MB,
    //   AO 16.8MB (=Xb alias), WoT 8.4MB (wo^T; written during gemm1 by the
    //   64 idle-CU blocks -- Wt itself is read by gemm1 so can't be reused).
    char* ws = (char*)d_ws;
    unsigned short* Wt  = (unsigned short*)ws; ws += 3072L * 2048 * 2;
    float*          bsf = (float*)ws;          ws += 3072L * 4;
    unsigned int*   Tab = (unsigned int*)ws;   ws += 4096L * 64 * 4;
    unsigned short* Qr  = (unsigned short*)ws; ws += (long)BATCH * NH  * S_LEN * HD * 2;
    unsigned short* Kr  = (unsigned short*)ws; ws += (long)BATCH * NKV * S_LEN * HD * 2;
    unsigned short* Vt  = (unsigned short*)ws; ws += (long)BATCH * NKV * HD * S_LEN * 2;
    unsigned short* AO  = (unsigned short*)ws; ws += 4096L * 2048 * 2;
    unsigned short* WoT = (unsigned short*)ws; ws += 2048L * 2048 * 2;
    unsigned short* Xb  = AO;   // alias: Xb dead (post-gemm1) before attn writes AO

    prep_all<<<10240, 256, 0, stream>>>(X, Xb, bq, bk, bv, bsf, tv, rw, Tab,
                                        wq, wk, wv, Wt);
    gemm_qkv_rope<<<dim3(16, 16), 512, 0, stream>>>(Xb, Wt, bsf, Tab, Qr, Kr, Vt,
                                                    wo, WoT);
    attn_kernel<<<dim3(32, 16, 1), 512, 0, stream>>>(Qr, Kr, Vt, AO);
    gemm_o<<<dim3(8, 32), 512, 0, stream>>>(AO, WoT, (float*)d_out);
}